// Round 5
// baseline (477.738 us; speedup 1.0000x reference)
//
#include <hip/hip_runtime.h>

// ---------------------------------------------------------------------------
// GAT 2-layer encoder. N=100k nodes, E=1.6M edges, 128->128(relu)->64.
//   a_dst = x . (W_dst @ att_dst)  (h_dst never materialized)
//   CSR-by-dst via two-level counting sort (write-amp-free)
//   register-tiled fp32 GEMM (4x8 per thread, conflict-free LDS)
//   one wave per dst node: fused segment softmax + 8-way grouped gather
//   NT stores/loads on single-use streams so LLC retains the h_src gather set
// ---------------------------------------------------------------------------

typedef unsigned long long u64;
typedef float v4f __attribute__((ext_vector_type(4)));

__device__ __forceinline__ v4f ntload4(const float* p) {
    return __builtin_nontemporal_load((const v4f*)p);
}
__device__ __forceinline__ void ntstore4(float* p, v4f v) {
    __builtin_nontemporal_store(v, (v4f*)p);
}

__global__ void matvec_kernel(const float* __restrict__ W, const float* __restrict__ a,
                              float* __restrict__ out, int rows, int cols) {
    int i = blockIdx.x * blockDim.x + threadIdx.x;
    if (i >= rows) return;
    float s = 0.f;
    for (int j = 0; j < cols; ++j) s += W[i * cols + j] * a[j];
    out[i] = s;
}

// ---- CSR build: two-level counting sort ----
__global__ __launch_bounds__(256) void bhist_kernel(const int* __restrict__ dst,
                                                    int* __restrict__ gh, int E) {
    __shared__ int h[256];
    h[threadIdx.x] = 0;
    __syncthreads();
    int base = blockIdx.x * 4096;
    int lim = min(base + 4096, E);
    for (int i = base + threadIdx.x; i < lim; i += 256)
        atomicAdd(&h[__builtin_nontemporal_load(dst + i) >> 9], 1);
    __syncthreads();
    int v = h[threadIdx.x];
    if (v) atomicAdd(&gh[threadIdx.x], v);
}

__global__ __launch_bounds__(256) void bscan_kernel(const int* __restrict__ gh,
                                                    int* __restrict__ bbase,
                                                    int* __restrict__ gcur,
                                                    int* __restrict__ offs, int N, int E) {
    __shared__ int s[256];
    int t = threadIdx.x;
    int v = gh[t];
    s[t] = v;
    __syncthreads();
    for (int o = 1; o < 256; o <<= 1) {
        int u = (t >= o) ? s[t - o] : 0;
        __syncthreads();
        s[t] += u;
        __syncthreads();
    }
    int excl = s[t] - v;
    bbase[t] = excl;
    gcur[t] = excl;
    if (t == 255) { bbase[256] = E; offs[N] = E; }
}

__global__ __launch_bounds__(256) void bscatter_kernel(const int* __restrict__ src,
                                                       const int* __restrict__ dst,
                                                       int* __restrict__ gcur,
                                                       u64* __restrict__ pairs, int E) {
    __shared__ int h[256];
    __shared__ int rbase[256];
    const int tid = threadIdx.x;
    h[tid] = 0;
    __syncthreads();
    const int base = blockIdx.x * 4096;
    u64 pv[16];
    int rk[16];
    int bk[16];
#pragma unroll 16
    for (int k = 0; k < 16; ++k) {
        int i = base + k * 256 + tid;
        if (i < E) {
            int d = __builtin_nontemporal_load(dst + i);
            int b = d >> 9;
            bk[k] = b;
            pv[k] = ((u64)(unsigned)d << 32) | (unsigned)__builtin_nontemporal_load(src + i);
            rk[k] = atomicAdd(&h[b], 1);
        } else {
            bk[k] = -1;
        }
    }
    __syncthreads();
    int c = h[tid];
    rbase[tid] = c ? atomicAdd(&gcur[tid], c) : 0;
    __syncthreads();
#pragma unroll 16
    for (int k = 0; k < 16; ++k)
        if (bk[k] >= 0)
            __builtin_nontemporal_store(pv[k], pairs + (size_t)rbase[bk[k]] + rk[k]);
}

__global__ __launch_bounds__(512) void bsort_kernel(const u64* __restrict__ pairs,
                                                    const int* __restrict__ bbase,
                                                    int* __restrict__ offs,
                                                    int* __restrict__ srcs, int N) {
    __shared__ int h[512];
    __shared__ int cur[512];
    const int t = threadIdx.x;
    const int b = blockIdx.x;
    const int beg = bbase[b], end = bbase[b + 1];
    h[t] = 0;
    __syncthreads();
    for (int i = beg + t; i < end; i += 512)
        atomicAdd(&h[(int)(__builtin_nontemporal_load(pairs + i) >> 32) & 511], 1);
    __syncthreads();
    int v = h[t];
    cur[t] = v;
    __syncthreads();
    for (int o = 1; o < 512; o <<= 1) {
        int u = (t >= o) ? cur[t - o] : 0;
        __syncthreads();
        cur[t] += u;
        __syncthreads();
    }
    int pos0 = beg + cur[t] - v;
    __syncthreads();
    cur[t] = pos0;
    int g = (b << 9) + t;
    if (g < N) offs[g] = pos0;
    __syncthreads();
    for (int i = beg + t; i < end; i += 512) {
        u64 p = __builtin_nontemporal_load(pairs + i);
        int local = (int)(p >> 32) & 511;
        int pp = atomicAdd(&cur[local], 1);
        srcs[pp] = (int)(p & 0xffffffffu);
    }
}

// H = X @ W  (X:[M,128], W:[128,C]); fused epilogue:
//   aS[m] = H[m,:] . attS     aD[m] = X[m,:] . wda
template <int C>
__global__ __launch_bounds__(256) void gemm_att_kernel(
    const float* __restrict__ X, const float* __restrict__ W,
    const float* __restrict__ attS, const float* __restrict__ wda,
    float* __restrict__ H, float* __restrict__ aS, float* __restrict__ aD, int M) {
    constexpr int NB = (C == 128) ? 2 : 1;
    __shared__ float4 Xs[16 * 65];          // [k4][row], coeff 65 rotates banks
    __shared__ float  Ws[64 * C];           // k-major half of W

    const int t  = threadIdx.x;
    const int m0 = blockIdx.x * 64;
    const int rg = t >> 4;                  // 0..15 row group
    const int cg = t & 15;                  // 0..15 col group

    float4 acc[4][NB];
#pragma unroll
    for (int j = 0; j < 4; ++j)
#pragma unroll
        for (int b = 0; b < NB; ++b) acc[j][b] = make_float4(0.f, 0.f, 0.f, 0.f);
    float pd[4] = {0.f, 0.f, 0.f, 0.f};

    for (int kk = 0; kk < 128; kk += 64) {
        {
            const float4* Wg = (const float4*)(W + (size_t)kk * C);
            float4* WsV = (float4*)Ws;
#pragma unroll
            for (int i = 0; i < C / 16; ++i) WsV[i * 256 + t] = Wg[i * 256 + t];
        }
#pragma unroll
        for (int i = 0; i < 4; ++i) {
            int f4 = i * 256 + t;
            int row = f4 >> 4;
            int k4 = f4 & 15;
            int gr = m0 + row;
            float4 fv = make_float4(0.f, 0.f, 0.f, 0.f);
            if (gr < M) {
                v4f v = ntload4(X + (size_t)gr * 128 + kk + k4 * 4);  // single-use stream
                fv = make_float4(v.x, v.y, v.z, v.w);
            }
            Xs[k4 * 65 + row] = fv;
        }
        __syncthreads();

#pragma unroll 4
        for (int k4 = 0; k4 < 16; ++k4) {
            float4 a[4];
#pragma unroll
            for (int j = 0; j < 4; ++j) a[j] = Xs[k4 * 65 + rg * 4 + j];
            const float* wrow = Ws + k4 * 4 * C;
            const float* wd = wda + kk + k4 * 4;
#pragma unroll
            for (int u = 0; u < 4; ++u) {
                float4 b0 = *(const float4*)(wrow + u * C + cg * 4);
                float wdu = wd[u];
                float av[4];
#pragma unroll
                for (int j = 0; j < 4; ++j) av[j] = ((const float*)&a[j])[u];
#pragma unroll
                for (int j = 0; j < 4; ++j) {
                    acc[j][0].x += av[j] * b0.x;
                    acc[j][0].y += av[j] * b0.y;
                    acc[j][0].z += av[j] * b0.z;
                    acc[j][0].w += av[j] * b0.w;
                    pd[j] += av[j] * wdu;
                }
                if constexpr (NB == 2) {
                    float4 b1 = *(const float4*)(wrow + u * C + 64 + cg * 4);
#pragma unroll
                    for (int j = 0; j < 4; ++j) {
                        acc[j][1].x += av[j] * b1.x;
                        acc[j][1].y += av[j] * b1.y;
                        acc[j][1].z += av[j] * b1.z;
                        acc[j][1].w += av[j] * b1.w;
                    }
                }
            }
        }
        __syncthreads();
    }

    float4 as0 = *(const float4*)(attS + cg * 4);
    float4 as1 = make_float4(0.f, 0.f, 0.f, 0.f);
    if constexpr (NB == 2) as1 = *(const float4*)(attS + 64 + cg * 4);
#pragma unroll
    for (int j = 0; j < 4; ++j) {
        int gr = m0 + rg * 4 + j;
        bool ok = gr < M;
        if (ok) {
            *(float4*)(H + (size_t)gr * C + cg * 4) = acc[j][0];   // keep in LLC (reused)
            if constexpr (NB == 2)
                *(float4*)(H + (size_t)gr * C + 64 + cg * 4) = acc[j][1];
        }
        float ps = acc[j][0].x * as0.x + acc[j][0].y * as0.y +
                   acc[j][0].z * as0.z + acc[j][0].w * as0.w;
        if constexpr (NB == 2)
            ps += acc[j][1].x * as1.x + acc[j][1].y * as1.y +
                  acc[j][1].z * as1.z + acc[j][1].w * as1.w;
#pragma unroll
        for (int o = 8; o; o >>= 1) ps += __shfl_xor(ps, o, 64);
        if (cg == 0 && ok) { aS[gr] = ps; aD[gr] = pd[j]; }
    }
}

// Grouped accumulate of one <=64-edge chunk: 8 groups of 8 lanes, each group
// handles one edge per step with 4 (C=128) / 2 (C=64) dwordx4 loads per lane.
template <int C>
__device__ __forceinline__ void agg_chunk(float w, int sj, int cnt, int lane,
                                          const float* __restrict__ hsrc, float* acc) {
    const int g = lane >> 3;
    const int l = lane & 7;
    const int jm = (cnt + 7) >> 3;
    for (int j = 0; j < jm; ++j) {
        int e = j * 8 + g;
        float wj = __shfl(w, e, 64);
        int sr = __shfl(sj, e, 64);
        if (e < cnt) {
            if constexpr (C == 128) {
                const v4f* p = (const v4f*)(hsrc + ((size_t)sr << 7)) + l * 4;
                v4f v0 = p[0], v1 = p[1], v2 = p[2], v3 = p[3];
                acc[0]  += wj * v0.x; acc[1]  += wj * v0.y; acc[2]  += wj * v0.z; acc[3]  += wj * v0.w;
                acc[4]  += wj * v1.x; acc[5]  += wj * v1.y; acc[6]  += wj * v1.z; acc[7]  += wj * v1.w;
                acc[8]  += wj * v2.x; acc[9]  += wj * v2.y; acc[10] += wj * v2.z; acc[11] += wj * v2.w;
                acc[12] += wj * v3.x; acc[13] += wj * v3.y; acc[14] += wj * v3.z; acc[15] += wj * v3.w;
            } else {
                const v4f* p = (const v4f*)(hsrc + ((size_t)sr << 6)) + l * 2;
                v4f v0 = p[0], v1 = p[1];
                acc[0] += wj * v0.x; acc[1] += wj * v0.y; acc[2] += wj * v0.z; acc[3] += wj * v0.w;
                acc[4] += wj * v1.x; acc[5] += wj * v1.y; acc[6] += wj * v1.z; acc[7] += wj * v1.w;
            }
        }
    }
}

// One wave per destination node: segment softmax + weighted aggregation.
template <int C, bool RELU>
__global__ __launch_bounds__(256) void aggregate_kernel(
    const int* __restrict__ offs, const int* __restrict__ srcs,
    const float* __restrict__ hsrc, const float* __restrict__ aS,
    const float* __restrict__ aD, const float* __restrict__ bias,
    float* __restrict__ out, int n) {
    int node = (int)((blockIdx.x * blockDim.x + threadIdx.x) >> 6);
    int lane = threadIdx.x & 63;
    if (node >= n) return;
    int beg = offs[node], end = offs[node + 1];
    int deg = end - beg;
    float ad = aD[node];

    constexpr int NA = (C == 128) ? 16 : 8;
    float acc[NA];
#pragma unroll
    for (int i = 0; i < NA; ++i) acc[i] = 0.f;

    if (deg <= 64) {
        int i = beg + lane;
        int sj = 0;
        float lv = -INFINITY;
        if (i < end) {
            sj = __builtin_nontemporal_load(srcs + i);
            float l = aS[sj] + ad;
            lv = (l > 0.f) ? l : 0.2f * l;
        }
        float m = lv;
#pragma unroll
        for (int o = 32; o; o >>= 1) m = fmaxf(m, __shfl_xor(m, o, 64));
        float e = (i < end) ? __expf(lv - m) : 0.f;
        float s = e;
#pragma unroll
        for (int o = 32; o; o >>= 1) s += __shfl_xor(s, o, 64);
        float w = e * (1.f / (s + 1e-16f));
        agg_chunk<C>(w, sj, deg, lane, hsrc, acc);
    } else {
        float m = -INFINITY;
        for (int i = beg + lane; i < end; i += 64) {
            float l = aS[srcs[i]] + ad;
            l = (l > 0.f) ? l : 0.2f * l;
            m = fmaxf(m, l);
        }
#pragma unroll
        for (int o = 32; o; o >>= 1) m = fmaxf(m, __shfl_xor(m, o, 64));
        float s = 0.f;
        for (int i = beg + lane; i < end; i += 64) {
            float l = aS[srcs[i]] + ad;
            l = (l > 0.f) ? l : 0.2f * l;
            s += __expf(l - m);
        }
#pragma unroll
        for (int o = 32; o; o >>= 1) s += __shfl_xor(s, o, 64);
        float inv = 1.f / (s + 1e-16f);
        for (int base = beg; base < end; base += 64) {
            int i = base + lane;
            int sj = 0;
            float w = 0.f;
            if (i < end) {
                sj = srcs[i];
                float l = aS[sj] + ad;
                l = (l > 0.f) ? l : 0.2f * l;
                w = __expf(l - m) * inv;
            }
            agg_chunk<C>(w, sj, min(64, end - base), lane, hsrc, acc);
        }
    }

    // cross-group reduce over lane bits 3..5
#pragma unroll
    for (int i = 0; i < NA; ++i) {
        acc[i] += __shfl_xor(acc[i], 8, 64);
        acc[i] += __shfl_xor(acc[i], 16, 64);
        acc[i] += __shfl_xor(acc[i], 32, 64);
    }

    if (lane < 8) {
        if constexpr (C == 128) {
            int c0 = lane * 16;
            float* op = out + (size_t)node * 128 + c0;
            const float* bp = bias + c0;
#pragma unroll
            for (int q = 0; q < 4; ++q) {
                v4f b = *(const v4f*)(bp + q * 4);
                v4f o;
                o.x = acc[q * 4 + 0] + b.x;
                o.y = acc[q * 4 + 1] + b.y;
                o.z = acc[q * 4 + 2] + b.z;
                o.w = acc[q * 4 + 3] + b.w;
                if (RELU) {
                    o.x = fmaxf(o.x, 0.f); o.y = fmaxf(o.y, 0.f);
                    o.z = fmaxf(o.z, 0.f); o.w = fmaxf(o.w, 0.f);
                }
                ntstore4(op + q * 4, o);
            }
        } else {
            int c0 = lane * 8;
            float* op = out + (size_t)node * 64 + c0;
            const float* bp = bias + c0;
#pragma unroll
            for (int q = 0; q < 2; ++q) {
                v4f b = *(const v4f*)(bp + q * 4);
                v4f o;
                o.x = acc[q * 4 + 0] + b.x;
                o.y = acc[q * 4 + 1] + b.y;
                o.z = acc[q * 4 + 2] + b.z;
                o.w = acc[q * 4 + 3] + b.w;
                if (RELU) {
                    o.x = fmaxf(o.x, 0.f); o.y = fmaxf(o.y, 0.f);
                    o.z = fmaxf(o.z, 0.f); o.w = fmaxf(o.w, 0.f);
                }
                ntstore4(op + q * 4, o);
            }
        }
    }
}

extern "C" void kernel_launch(void* const* d_in, const int* in_sizes, int n_in,
                              void* d_out, int out_size, void* d_ws, size_t ws_size,
                              hipStream_t stream) {
    const float* x     = (const float*)d_in[0];
    const int*   edge  = (const int*)d_in[1];
    const float* W1s   = (const float*)d_in[2];
    const float* W1d   = (const float*)d_in[3];
    const float* att1s = (const float*)d_in[4];
    const float* att1d = (const float*)d_in[5];
    const float* b1    = (const float*)d_in[6];
    const float* W2s   = (const float*)d_in[7];
    const float* W2d   = (const float*)d_in[8];
    const float* att2s = (const float*)d_in[9];
    const float* att2d = (const float*)d_in[10];
    const float* b2    = (const float*)d_in[11];

    const int N = in_sizes[0] / 128;
    const int E = in_sizes[1] / 2;
    const int* srcI = edge;
    const int* dstI = edge + E;

    size_t off = 0;
    auto alloc = [&](size_t bytes) {
        void* p = (char*)d_ws + off;
        off += (bytes + 255) & ~(size_t)255;
        return p;
    };
    int*   offs  = (int*)alloc((size_t)(N + 1) * 4);
    int*   srcs  = (int*)alloc((size_t)E * 4);
    int*   gh    = (int*)alloc(256 * 4);
    int*   bbase = (int*)alloc(257 * 4);
    int*   gcur  = (int*)alloc(256 * 4);
    float* watt1 = (float*)alloc(128 * 4);
    float* watt2 = (float*)alloc(128 * 4);
    float* a_s   = (float*)alloc((size_t)N * 4);
    float* a_d   = (float*)alloc((size_t)N * 4);
    float* h_s   = (float*)alloc((size_t)N * 128 * 4);  // h1_src then h2_src
    float* h1    = (float*)alloc((size_t)N * 128 * 4);  // relu(layer1 out)
    u64*   pairs = (u64*)h_s;   // dead before gemm1 writes h_s

    hipMemsetAsync(gh, 0, 256 * 4, stream);
    matvec_kernel<<<1, 128, 0, stream>>>(W1d, att1d, watt1, 128, 128);
    matvec_kernel<<<1, 128, 0, stream>>>(W2d, att2d, watt2, 128, 64);

    const int nbE = (E + 4095) / 4096;
    const int nbuckets = (N + 511) >> 9;
    bhist_kernel<<<nbE, 256, 0, stream>>>(dstI, gh, E);
    bscan_kernel<<<1, 256, 0, stream>>>(gh, bbase, gcur, offs, N, E);
    bscatter_kernel<<<nbE, 256, 0, stream>>>(srcI, dstI, gcur, pairs, E);
    bsort_kernel<<<nbuckets, 512, 0, stream>>>(pairs, bbase, offs, srcs, N);

    int gblk = (N + 63) / 64;
    gemm_att_kernel<128><<<gblk, 256, 0, stream>>>(x, W1s, att1s, watt1, h_s, a_s, a_d, N);
    aggregate_kernel<128, true><<<(N + 3) / 4, 256, 0, stream>>>(offs, srcs, h_s, a_s, a_d, b1, h1, N);
    gemm_att_kernel<64><<<gblk, 256, 0, stream>>>(h1, W2s, att2s, watt2, h_s, a_s, a_d, N);
    aggregate_kernel<64, false><<<(N + 3) / 4, 256, 0, stream>>>(offs, srcs, h_s, a_s, a_d, b2, (float*)d_out, N);
}

// Round 6
// 444.146 us; speedup vs baseline: 1.0756x; 1.0756x over previous
//
#include <hip/hip_runtime.h>

// ---------------------------------------------------------------------------
// GAT 2-layer encoder. N=100k nodes, E=1.6M edges, 128->128(relu)->64.
//   a_dst = x . (W_dst @ att_dst)  (h_dst never materialized)
//   CSR-by-dst via two-level counting sort (write-amp-free)
//   register-tiled fp32 GEMM (4x8 per thread, conflict-free LDS)
//   layer-1 h_src stored bf16 (halves the dominant random-gather stream;
//   error is attenuated through layer-2's K=128 contraction)
//   one wave per dst node: fused segment softmax + 8-way grouped gather,
//   2-step unrolled for MLP
// ---------------------------------------------------------------------------

typedef unsigned long long u64;
typedef float v4f __attribute__((ext_vector_type(4)));

__device__ __forceinline__ void ntstore4(float* p, v4f v) {
    __builtin_nontemporal_store(v, (v4f*)p);
}
__device__ __forceinline__ float bflo(unsigned u) { return __uint_as_float(u << 16); }
__device__ __forceinline__ float bfhi(unsigned u) { return __uint_as_float(u & 0xffff0000u); }
__device__ __forceinline__ unsigned bf16pair(float a, float b) {  // rne pack
    unsigned ua = __float_as_uint(a), ub = __float_as_uint(b);
    ua = (ua + 0x7fffu + ((ua >> 16) & 1u)) >> 16;
    ub = (ub + 0x7fffu + ((ub >> 16) & 1u)) >> 16;
    return ua | (ub << 16);
}
__device__ __forceinline__ void fma_bf16_8(float* acc, uint4 q, float w) {
    const unsigned* u = (const unsigned*)&q;
#pragma unroll
    for (int i = 0; i < 4; ++i) {
        acc[2 * i]     += w * bflo(u[i]);
        acc[2 * i + 1] += w * bfhi(u[i]);
    }
}

__global__ void matvec_kernel(const float* __restrict__ W, const float* __restrict__ a,
                              float* __restrict__ out, int rows, int cols) {
    int i = blockIdx.x * blockDim.x + threadIdx.x;
    if (i >= rows) return;
    float s = 0.f;
    for (int j = 0; j < cols; ++j) s += W[i * cols + j] * a[j];
    out[i] = s;
}

// ---- CSR build: two-level counting sort ----
__global__ __launch_bounds__(256) void bhist_kernel(const int* __restrict__ dst,
                                                    int* __restrict__ gh, int E) {
    __shared__ int h[256];
    h[threadIdx.x] = 0;
    __syncthreads();
    int base = blockIdx.x * 4096;
    int lim = min(base + 4096, E);
    for (int i = base + threadIdx.x; i < lim; i += 256)
        atomicAdd(&h[__builtin_nontemporal_load(dst + i) >> 9], 1);
    __syncthreads();
    int v = h[threadIdx.x];
    if (v) atomicAdd(&gh[threadIdx.x], v);
}

__global__ __launch_bounds__(256) void bscan_kernel(const int* __restrict__ gh,
                                                    int* __restrict__ bbase,
                                                    int* __restrict__ gcur,
                                                    int* __restrict__ offs, int N, int E) {
    __shared__ int s[256];
    int t = threadIdx.x;
    int v = gh[t];
    s[t] = v;
    __syncthreads();
    for (int o = 1; o < 256; o <<= 1) {
        int u = (t >= o) ? s[t - o] : 0;
        __syncthreads();
        s[t] += u;
        __syncthreads();
    }
    int excl = s[t] - v;
    bbase[t] = excl;
    gcur[t] = excl;
    if (t == 255) { bbase[256] = E; offs[N] = E; }
}

__global__ __launch_bounds__(256) void bscatter_kernel(const int* __restrict__ src,
                                                       const int* __restrict__ dst,
                                                       int* __restrict__ gcur,
                                                       u64* __restrict__ pairs, int E) {
    __shared__ int h[256];
    __shared__ int rbase[256];
    const int tid = threadIdx.x;
    h[tid] = 0;
    __syncthreads();
    const int base = blockIdx.x * 4096;
    u64 pv[16];
    int rk[16];
    int bk[16];
#pragma unroll 16
    for (int k = 0; k < 16; ++k) {
        int i = base + k * 256 + tid;
        if (i < E) {
            int d = __builtin_nontemporal_load(dst + i);
            int b = d >> 9;
            bk[k] = b;
            pv[k] = ((u64)(unsigned)d << 32) | (unsigned)__builtin_nontemporal_load(src + i);
            rk[k] = atomicAdd(&h[b], 1);
        } else {
            bk[k] = -1;
        }
    }
    __syncthreads();
    int c = h[tid];
    rbase[tid] = c ? atomicAdd(&gcur[tid], c) : 0;
    __syncthreads();
#pragma unroll 16
    for (int k = 0; k < 16; ++k)
        if (bk[k] >= 0)
            __builtin_nontemporal_store(pv[k], pairs + (size_t)rbase[bk[k]] + rk[k]);
}

__global__ __launch_bounds__(512) void bsort_kernel(const u64* __restrict__ pairs,
                                                    const int* __restrict__ bbase,
                                                    int* __restrict__ offs,
                                                    int* __restrict__ srcs, int N) {
    __shared__ int h[512];
    __shared__ int cur[512];
    const int t = threadIdx.x;
    const int b = blockIdx.x;
    const int beg = bbase[b], end = bbase[b + 1];
    h[t] = 0;
    __syncthreads();
    for (int i = beg + t; i < end; i += 512)
        atomicAdd(&h[(int)(__builtin_nontemporal_load(pairs + i) >> 32) & 511], 1);
    __syncthreads();
    int v = h[t];
    cur[t] = v;
    __syncthreads();
    for (int o = 1; o < 512; o <<= 1) {
        int u = (t >= o) ? cur[t - o] : 0;
        __syncthreads();
        cur[t] += u;
        __syncthreads();
    }
    int pos0 = beg + cur[t] - v;
    __syncthreads();
    cur[t] = pos0;
    int g = (b << 9) + t;
    if (g < N) offs[g] = pos0;
    __syncthreads();
    for (int i = beg + t; i < end; i += 512) {
        u64 p = __builtin_nontemporal_load(pairs + i);
        int local = (int)(p >> 32) & 511;
        int pp = atomicAdd(&cur[local], 1);
        srcs[pp] = (int)(p & 0xffffffffu);
    }
}

// H = X @ W  (X:[M,128], W:[128,C]); fused epilogue:
//   aS[m] = H[m,:] . attS     aD[m] = X[m,:] . wda
// BF16OUT: H stored as packed bf16 rows (C=128 only).
template <int C, bool BF16OUT>
__global__ __launch_bounds__(256) void gemm_att_kernel(
    const float* __restrict__ X, const float* __restrict__ W,
    const float* __restrict__ attS, const float* __restrict__ wda,
    float* __restrict__ H, float* __restrict__ aS, float* __restrict__ aD, int M) {
    constexpr int NB = (C == 128) ? 2 : 1;
    __shared__ float4 Xs[16 * 65];          // [k4][row], coeff 65 rotates banks
    __shared__ float  Ws[64 * C];           // k-major half of W

    const int t  = threadIdx.x;
    const int m0 = blockIdx.x * 64;
    const int rg = t >> 4;                  // 0..15 row group
    const int cg = t & 15;                  // 0..15 col group

    float4 acc[4][NB];
#pragma unroll
    for (int j = 0; j < 4; ++j)
#pragma unroll
        for (int b = 0; b < NB; ++b) acc[j][b] = make_float4(0.f, 0.f, 0.f, 0.f);
    float pd[4] = {0.f, 0.f, 0.f, 0.f};

    for (int kk = 0; kk < 128; kk += 64) {
        {
            const float4* Wg = (const float4*)(W + (size_t)kk * C);
            float4* WsV = (float4*)Ws;
#pragma unroll
            for (int i = 0; i < C / 16; ++i) WsV[i * 256 + t] = Wg[i * 256 + t];
        }
#pragma unroll
        for (int i = 0; i < 4; ++i) {
            int f4 = i * 256 + t;
            int row = f4 >> 4;
            int k4 = f4 & 15;
            int gr = m0 + row;
            float4 v = make_float4(0.f, 0.f, 0.f, 0.f);
            if (gr < M) v = *(const float4*)(X + (size_t)gr * 128 + kk + k4 * 4);
            Xs[k4 * 65 + row] = v;
        }
        __syncthreads();

#pragma unroll 4
        for (int k4 = 0; k4 < 16; ++k4) {
            float4 a[4];
#pragma unroll
            for (int j = 0; j < 4; ++j) a[j] = Xs[k4 * 65 + rg * 4 + j];
            const float* wrow = Ws + k4 * 4 * C;
            const float* wd = wda + kk + k4 * 4;
#pragma unroll
            for (int u = 0; u < 4; ++u) {
                float4 b0 = *(const float4*)(wrow + u * C + cg * 4);
                float wdu = wd[u];
                float av[4];
#pragma unroll
                for (int j = 0; j < 4; ++j) av[j] = ((const float*)&a[j])[u];
#pragma unroll
                for (int j = 0; j < 4; ++j) {
                    acc[j][0].x += av[j] * b0.x;
                    acc[j][0].y += av[j] * b0.y;
                    acc[j][0].z += av[j] * b0.z;
                    acc[j][0].w += av[j] * b0.w;
                    pd[j] += av[j] * wdu;
                }
                if constexpr (NB == 2) {
                    float4 b1 = *(const float4*)(wrow + u * C + 64 + cg * 4);
#pragma unroll
                    for (int j = 0; j < 4; ++j) {
                        acc[j][1].x += av[j] * b1.x;
                        acc[j][1].y += av[j] * b1.y;
                        acc[j][1].z += av[j] * b1.z;
                        acc[j][1].w += av[j] * b1.w;
                    }
                }
            }
        }
        __syncthreads();
    }

    float4 as0 = *(const float4*)(attS + cg * 4);
    float4 as1 = make_float4(0.f, 0.f, 0.f, 0.f);
    if constexpr (NB == 2) as1 = *(const float4*)(attS + 64 + cg * 4);
#pragma unroll
    for (int j = 0; j < 4; ++j) {
        int gr = m0 + rg * 4 + j;
        bool ok = gr < M;
        if (ok) {
            if constexpr (BF16OUT) {
                unsigned* Hb = (unsigned*)H + ((size_t)gr << 6);   // 64 uints/row
                uint2 u0, u1;
                u0.x = bf16pair(acc[j][0].x, acc[j][0].y);
                u0.y = bf16pair(acc[j][0].z, acc[j][0].w);
                *(uint2*)(Hb + cg * 2) = u0;
                u1.x = bf16pair(acc[j][1].x, acc[j][1].y);
                u1.y = bf16pair(acc[j][1].z, acc[j][1].w);
                *(uint2*)(Hb + 32 + cg * 2) = u1;
            } else {
                *(float4*)(H + (size_t)gr * C + cg * 4) = acc[j][0];
                if constexpr (NB == 2)
                    *(float4*)(H + (size_t)gr * C + 64 + cg * 4) = acc[j][1];
            }
        }
        float ps = acc[j][0].x * as0.x + acc[j][0].y * as0.y +
                   acc[j][0].z * as0.z + acc[j][0].w * as0.w;
        if constexpr (NB == 2)
            ps += acc[j][1].x * as1.x + acc[j][1].y * as1.y +
                  acc[j][1].z * as1.z + acc[j][1].w * as1.w;
#pragma unroll
        for (int o = 8; o; o >>= 1) ps += __shfl_xor(ps, o, 64);
        if (cg == 0 && ok) { aS[gr] = ps; aD[gr] = pd[j]; }
    }
}

// One wave per destination node: segment softmax + weighted aggregation.
// 8 groups of 8 lanes; each group covers one edge's row per step; 2-step
// unroll keeps 4 row-fragments in flight per lane.
// BF16 rows: 16 uint4/row (C=128).  F32 rows: 16 v4f/row (C=64).
template <bool BF16, int C, bool RELU, bool NTOUT>
__global__ __launch_bounds__(256) void aggregate_kernel(
    const int* __restrict__ offs, const int* __restrict__ srcs,
    const void* __restrict__ hsrc, const float* __restrict__ aS,
    const float* __restrict__ aD, const float* __restrict__ bias,
    float* __restrict__ out, int n) {
    int node = (int)((blockIdx.x * blockDim.x + threadIdx.x) >> 6);
    int lane = threadIdx.x & 63;
    if (node >= n) return;
    int beg = offs[node], end = offs[node + 1];
    int deg = end - beg;
    float ad = aD[node];
    const int g = lane >> 3;
    const int l = lane & 7;

    constexpr int NA = (C == 128) ? 16 : 8;
    float acc[NA];
#pragma unroll
    for (int i = 0; i < NA; ++i) acc[i] = 0.f;

    auto do_steps = [&](float w, int sj, int cnt) {
        int jm = (cnt + 7) >> 3;
        for (int j = 0; j < jm; j += 2) {
            int e0 = j * 8 + g, e1 = e0 + 8;
            float w0 = __shfl(w, e0, 64), w1 = __shfl(w, e1, 64);
            int s0 = __shfl(sj, e0, 64), s1 = __shfl(sj, e1, 64);
            bool v0 = e0 < cnt, v1 = e1 < cnt;
            if constexpr (BF16) {
                const uint4* p0 = (const uint4*)hsrc + (((size_t)s0) << 4) + l * 2;
                const uint4* p1 = (const uint4*)hsrc + (((size_t)s1) << 4) + l * 2;
                uint4 a0, a1, b0, b1;
                if (v0) { a0 = p0[0]; a1 = p0[1]; }
                if (v1) { b0 = p1[0]; b1 = p1[1]; }
                if (v0) { fma_bf16_8(acc, a0, w0); fma_bf16_8(acc + 8, a1, w0); }
                if (v1) { fma_bf16_8(acc, b0, w1); fma_bf16_8(acc + 8, b1, w1); }
            } else {
                const v4f* p0 = (const v4f*)hsrc + (((size_t)s0) << 4) + l * 2;
                const v4f* p1 = (const v4f*)hsrc + (((size_t)s1) << 4) + l * 2;
                v4f a0, a1, b0, b1;
                if (v0) { a0 = p0[0]; a1 = p0[1]; }
                if (v1) { b0 = p1[0]; b1 = p1[1]; }
                if (v0) {
                    acc[0] += w0 * a0.x; acc[1] += w0 * a0.y; acc[2] += w0 * a0.z; acc[3] += w0 * a0.w;
                    acc[4] += w0 * a1.x; acc[5] += w0 * a1.y; acc[6] += w0 * a1.z; acc[7] += w0 * a1.w;
                }
                if (v1) {
                    acc[0] += w1 * b0.x; acc[1] += w1 * b0.y; acc[2] += w1 * b0.z; acc[3] += w1 * b0.w;
                    acc[4] += w1 * b1.x; acc[5] += w1 * b1.y; acc[6] += w1 * b1.z; acc[7] += w1 * b1.w;
                }
            }
        }
    };

    if (deg <= 64) {
        int i = beg + lane;
        int sj = 0;
        float lv = -INFINITY;
        if (i < end) {
            sj = __builtin_nontemporal_load(srcs + i);
            float lg = aS[sj] + ad;
            lv = (lg > 0.f) ? lg : 0.2f * lg;
        }
        float m = lv;
#pragma unroll
        for (int o = 32; o; o >>= 1) m = fmaxf(m, __shfl_xor(m, o, 64));
        float e = (i < end) ? __expf(lv - m) : 0.f;
        float s = e;
#pragma unroll
        for (int o = 32; o; o >>= 1) s += __shfl_xor(s, o, 64);
        float w = e * (1.f / (s + 1e-16f));
        do_steps(w, sj, deg);
    } else {
        float m = -INFINITY;
        for (int i = beg + lane; i < end; i += 64) {
            float lg = aS[srcs[i]] + ad;
            lg = (lg > 0.f) ? lg : 0.2f * lg;
            m = fmaxf(m, lg);
        }
#pragma unroll
        for (int o = 32; o; o >>= 1) m = fmaxf(m, __shfl_xor(m, o, 64));
        float s = 0.f;
        for (int i = beg + lane; i < end; i += 64) {
            float lg = aS[srcs[i]] + ad;
            lg = (lg > 0.f) ? lg : 0.2f * lg;
            s += __expf(lg - m);
        }
#pragma unroll
        for (int o = 32; o; o >>= 1) s += __shfl_xor(s, o, 64);
        float inv = 1.f / (s + 1e-16f);
        for (int base = beg; base < end; base += 64) {
            int i = base + lane;
            int sj = 0;
            float w = 0.f;
            if (i < end) {
                sj = srcs[i];
                float lg = aS[sj] + ad;
                lg = (lg > 0.f) ? lg : 0.2f * lg;
                w = __expf(lg - m) * inv;
            }
            do_steps(w, sj, min(64, end - base));
        }
    }

    // cross-group reduce over lane bits 3..5
#pragma unroll
    for (int i = 0; i < NA; ++i) {
        acc[i] += __shfl_xor(acc[i], 8, 64);
        acc[i] += __shfl_xor(acc[i], 16, 64);
        acc[i] += __shfl_xor(acc[i], 32, 64);
    }

    if (lane < 8) {
        constexpr int PC = NA / 4;         // float4s per lane
        int c0 = lane * NA;
        float* op = out + (size_t)node * C + c0;
        const float* bp = bias + c0;
#pragma unroll
        for (int q = 0; q < PC; ++q) {
            v4f b = *(const v4f*)(bp + q * 4);
            v4f o;
            o.x = acc[q * 4 + 0] + b.x;
            o.y = acc[q * 4 + 1] + b.y;
            o.z = acc[q * 4 + 2] + b.z;
            o.w = acc[q * 4 + 3] + b.w;
            if (RELU) {
                o.x = fmaxf(o.x, 0.f); o.y = fmaxf(o.y, 0.f);
                o.z = fmaxf(o.z, 0.f); o.w = fmaxf(o.w, 0.f);
            }
            if (NTOUT) ntstore4(op + q * 4, o);
            else *(v4f*)(op + q * 4) = o;
        }
    }
}

extern "C" void kernel_launch(void* const* d_in, const int* in_sizes, int n_in,
                              void* d_out, int out_size, void* d_ws, size_t ws_size,
                              hipStream_t stream) {
    const float* x     = (const float*)d_in[0];
    const int*   edge  = (const int*)d_in[1];
    const float* W1s   = (const float*)d_in[2];
    const float* W1d   = (const float*)d_in[3];
    const float* att1s = (const float*)d_in[4];
    const float* att1d = (const float*)d_in[5];
    const float* b1    = (const float*)d_in[6];
    const float* W2s   = (const float*)d_in[7];
    const float* W2d   = (const float*)d_in[8];
    const float* att2s = (const float*)d_in[9];
    const float* att2d = (const float*)d_in[10];
    const float* b2    = (const float*)d_in[11];

    const int N = in_sizes[0] / 128;
    const int E = in_sizes[1] / 2;
    const int* srcI = edge;
    const int* dstI = edge + E;

    size_t off = 0;
    auto alloc = [&](size_t bytes) {
        void* p = (char*)d_ws + off;
        off += (bytes + 255) & ~(size_t)255;
        return p;
    };
    int*   offs  = (int*)alloc((size_t)(N + 1) * 4);
    int*   srcs  = (int*)alloc((size_t)E * 4);
    int*   gh    = (int*)alloc(256 * 4);
    int*   bbase = (int*)alloc(257 * 4);
    int*   gcur  = (int*)alloc(256 * 4);
    float* watt1 = (float*)alloc(128 * 4);
    float* watt2 = (float*)alloc(128 * 4);
    float* a_s   = (float*)alloc((size_t)N * 4);
    float* a_d   = (float*)alloc((size_t)N * 4);
    float* h1b   = (float*)alloc((size_t)N * 128 * 2);  // layer-1 h_src, bf16
    float* h1    = (float*)alloc((size_t)N * 128 * 4);  // relu(layer1 out), f32
    float* h2    = (float*)alloc((size_t)N * 64 * 4);   // layer-2 h_src, f32
    u64*   pairs = (u64*)h2;   // dead until gemm2 writes h2 (bsort << gemm2)

    hipMemsetAsync(gh, 0, 256 * 4, stream);
    matvec_kernel<<<1, 128, 0, stream>>>(W1d, att1d, watt1, 128, 128);
    matvec_kernel<<<1, 128, 0, stream>>>(W2d, att2d, watt2, 128, 64);

    const int nbE = (E + 4095) / 4096;
    const int nbuckets = (N + 511) >> 9;
    bhist_kernel<<<nbE, 256, 0, stream>>>(dstI, gh, E);
    bscan_kernel<<<1, 256, 0, stream>>>(gh, bbase, gcur, offs, N, E);
    bscatter_kernel<<<nbE, 256, 0, stream>>>(srcI, dstI, gcur, pairs, E);
    bsort_kernel<<<nbuckets, 512, 0, stream>>>(pairs, bbase, offs, srcs, N);

    int gblk = (N + 63) / 64;
    gemm_att_kernel<128, true><<<gblk, 256, 0, stream>>>(x, W1s, att1s, watt1, h1b, a_s, a_d, N);
    aggregate_kernel<true, 128, true, false><<<(N + 3) / 4, 256, 0, stream>>>(
        offs, srcs, h1b, a_s, a_d, b1, h1, N);
    gemm_att_kernel<64, false><<<gblk, 256, 0, stream>>>(h1, W2s, att2s, watt2, h2, a_s, a_d, N);
    aggregate_kernel<false, 64, false, true><<<(N + 3) / 4, 256, 0, stream>>>(
        offs, srcs, h2, a_s, a_d, b2, (float*)d_out, N);
}

// Round 7
// 414.272 us; speedup vs baseline: 1.1532x; 1.0721x over previous
//
#include <hip/hip_runtime.h>

// ---------------------------------------------------------------------------
// GAT 2-layer encoder. N=100k nodes, E=1.6M edges, 128->128(relu)->64.
//   a_dst = x . (W_dst @ att_dst)  (h_dst never materialized)
//   CSR-by-dst via two-level counting sort (write-amp-free)
//   register-tiled fp32 GEMM (4x8 per thread, conflict-free LDS)
//   BOTH gather arrays stored f16; aggregation inner loop uses
//   v_perm_b32 + v_dot2_f32_f16 (1 VALU per MAC, f32 accumulate)
//   one wave per dst node: fused segment softmax + 4x16 grouped gather,
//   4-step unrolled (16 edges in flight per wave)
// ---------------------------------------------------------------------------

typedef unsigned long long u64;
typedef float v4f __attribute__((ext_vector_type(4)));
typedef _Float16 v2h __attribute__((ext_vector_type(2)));

#define SEL_LO 0x01000504u   // (a.f16lo, b.f16lo)
#define SEL_HI 0x03020706u   // (a.f16hi, b.f16hi)

__device__ __forceinline__ void ntstore4(float* p, v4f v) {
    __builtin_nontemporal_store(v, (v4f*)p);
}
__device__ __forceinline__ unsigned h2pack(float a, float b) {
    v2h h;
    h.x = (_Float16)a;
    h.y = (_Float16)b;
    return __builtin_bit_cast(unsigned, h);
}
__device__ __forceinline__ float fdot2u(unsigned u, v2h w, float acc) {
    return __builtin_amdgcn_fdot2(__builtin_bit_cast(v2h, u), w, acc, false);
}

__global__ void matvec_kernel(const float* __restrict__ W, const float* __restrict__ a,
                              float* __restrict__ out, int rows, int cols) {
    int i = blockIdx.x * blockDim.x + threadIdx.x;
    if (i >= rows) return;
    float s = 0.f;
    for (int j = 0; j < cols; ++j) s += W[i * cols + j] * a[j];
    out[i] = s;
}

// ---- CSR build: two-level counting sort ----
__global__ __launch_bounds__(256) void bhist_kernel(const int* __restrict__ dst,
                                                    int* __restrict__ gh, int E) {
    __shared__ int h[256];
    h[threadIdx.x] = 0;
    __syncthreads();
    int base = blockIdx.x * 4096;
    int lim = min(base + 4096, E);
    for (int i = base + threadIdx.x; i < lim; i += 256)
        atomicAdd(&h[__builtin_nontemporal_load(dst + i) >> 9], 1);
    __syncthreads();
    int v = h[threadIdx.x];
    if (v) atomicAdd(&gh[threadIdx.x], v);
}

__global__ __launch_bounds__(256) void bscan_kernel(const int* __restrict__ gh,
                                                    int* __restrict__ bbase,
                                                    int* __restrict__ gcur,
                                                    int* __restrict__ offs, int N, int E) {
    __shared__ int s[256];
    int t = threadIdx.x;
    int v = gh[t];
    s[t] = v;
    __syncthreads();
    for (int o = 1; o < 256; o <<= 1) {
        int u = (t >= o) ? s[t - o] : 0;
        __syncthreads();
        s[t] += u;
        __syncthreads();
    }
    int excl = s[t] - v;
    bbase[t] = excl;
    gcur[t] = excl;
    if (t == 255) { bbase[256] = E; offs[N] = E; }
}

__global__ __launch_bounds__(256) void bscatter_kernel(const int* __restrict__ src,
                                                       const int* __restrict__ dst,
                                                       int* __restrict__ gcur,
                                                       u64* __restrict__ pairs, int E) {
    __shared__ int h[256];
    __shared__ int rbase[256];
    const int tid = threadIdx.x;
    h[tid] = 0;
    __syncthreads();
    const int base = blockIdx.x * 4096;
    u64 pv[16];
    int rk[16];
    int bk[16];
#pragma unroll 16
    for (int k = 0; k < 16; ++k) {
        int i = base + k * 256 + tid;
        if (i < E) {
            int d = __builtin_nontemporal_load(dst + i);
            int b = d >> 9;
            bk[k] = b;
            pv[k] = ((u64)(unsigned)d << 32) | (unsigned)__builtin_nontemporal_load(src + i);
            rk[k] = atomicAdd(&h[b], 1);
        } else {
            bk[k] = -1;
        }
    }
    __syncthreads();
    int c = h[tid];
    rbase[tid] = c ? atomicAdd(&gcur[tid], c) : 0;
    __syncthreads();
#pragma unroll 16
    for (int k = 0; k < 16; ++k)
        if (bk[k] >= 0)
            __builtin_nontemporal_store(pv[k], pairs + (size_t)rbase[bk[k]] + rk[k]);
}

__global__ __launch_bounds__(512) void bsort_kernel(const u64* __restrict__ pairs,
                                                    const int* __restrict__ bbase,
                                                    int* __restrict__ offs,
                                                    int* __restrict__ srcs, int N) {
    __shared__ int h[512];
    __shared__ int cur[512];
    const int t = threadIdx.x;
    const int b = blockIdx.x;
    const int beg = bbase[b], end = bbase[b + 1];
    h[t] = 0;
    __syncthreads();
    for (int i = beg + t; i < end; i += 512)
        atomicAdd(&h[(int)(__builtin_nontemporal_load(pairs + i) >> 32) & 511], 1);
    __syncthreads();
    int v = h[t];
    cur[t] = v;
    __syncthreads();
    for (int o = 1; o < 512; o <<= 1) {
        int u = (t >= o) ? cur[t - o] : 0;
        __syncthreads();
        cur[t] += u;
        __syncthreads();
    }
    int pos0 = beg + cur[t] - v;
    __syncthreads();
    cur[t] = pos0;
    int g = (b << 9) + t;
    if (g < N) offs[g] = pos0;
    __syncthreads();
    for (int i = beg + t; i < end; i += 512) {
        u64 p = __builtin_nontemporal_load(pairs + i);
        int local = (int)(p >> 32) & 511;
        int pp = atomicAdd(&cur[local], 1);
        srcs[pp] = (int)(p & 0xffffffffu);
    }
}

// H = X @ W  (X:[M,128], W:[128,C]); H stored packed f16. Fused epilogue:
//   aS[m] = H[m,:] . attS     aD[m] = X[m,:] . wda
template <int C>
__global__ __launch_bounds__(256) void gemm_att_kernel(
    const float* __restrict__ X, const float* __restrict__ W,
    const float* __restrict__ attS, const float* __restrict__ wda,
    unsigned* __restrict__ H, float* __restrict__ aS, float* __restrict__ aD, int M) {
    constexpr int NB = (C == 128) ? 2 : 1;
    __shared__ float4 Xs[16 * 65];          // [k4][row], coeff 65 rotates banks
    __shared__ float  Ws[64 * C];           // k-major half of W

    const int t  = threadIdx.x;
    const int m0 = blockIdx.x * 64;
    const int rg = t >> 4;                  // 0..15 row group
    const int cg = t & 15;                  // 0..15 col group

    float4 acc[4][NB];
#pragma unroll
    for (int j = 0; j < 4; ++j)
#pragma unroll
        for (int b = 0; b < NB; ++b) acc[j][b] = make_float4(0.f, 0.f, 0.f, 0.f);
    float pd[4] = {0.f, 0.f, 0.f, 0.f};

    for (int kk = 0; kk < 128; kk += 64) {
        {
            const float4* Wg = (const float4*)(W + (size_t)kk * C);
            float4* WsV = (float4*)Ws;
#pragma unroll
            for (int i = 0; i < C / 16; ++i) WsV[i * 256 + t] = Wg[i * 256 + t];
        }
#pragma unroll
        for (int i = 0; i < 4; ++i) {
            int f4 = i * 256 + t;
            int row = f4 >> 4;
            int k4 = f4 & 15;
            int gr = m0 + row;
            float4 v = make_float4(0.f, 0.f, 0.f, 0.f);
            if (gr < M) v = *(const float4*)(X + (size_t)gr * 128 + kk + k4 * 4);
            Xs[k4 * 65 + row] = v;
        }
        __syncthreads();

#pragma unroll 4
        for (int k4 = 0; k4 < 16; ++k4) {
            float4 a[4];
#pragma unroll
            for (int j = 0; j < 4; ++j) a[j] = Xs[k4 * 65 + rg * 4 + j];
            const float* wrow = Ws + k4 * 4 * C;
            const float* wd = wda + kk + k4 * 4;
#pragma unroll
            for (int u = 0; u < 4; ++u) {
                float4 b0 = *(const float4*)(wrow + u * C + cg * 4);
                float wdu = wd[u];
                float av[4];
#pragma unroll
                for (int j = 0; j < 4; ++j) av[j] = ((const float*)&a[j])[u];
#pragma unroll
                for (int j = 0; j < 4; ++j) {
                    acc[j][0].x += av[j] * b0.x;
                    acc[j][0].y += av[j] * b0.y;
                    acc[j][0].z += av[j] * b0.z;
                    acc[j][0].w += av[j] * b0.w;
                    pd[j] += av[j] * wdu;
                }
                if constexpr (NB == 2) {
                    float4 b1 = *(const float4*)(wrow + u * C + 64 + cg * 4);
#pragma unroll
                    for (int j = 0; j < 4; ++j) {
                        acc[j][1].x += av[j] * b1.x;
                        acc[j][1].y += av[j] * b1.y;
                        acc[j][1].z += av[j] * b1.z;
                        acc[j][1].w += av[j] * b1.w;
                    }
                }
            }
        }
        __syncthreads();
    }

    float4 as0 = *(const float4*)(attS + cg * 4);
    float4 as1 = make_float4(0.f, 0.f, 0.f, 0.f);
    if constexpr (NB == 2) as1 = *(const float4*)(attS + 64 + cg * 4);
#pragma unroll
    for (int j = 0; j < 4; ++j) {
        int gr = m0 + rg * 4 + j;
        bool ok = gr < M;
        if (ok) {
            unsigned* Hb = H + ((size_t)gr * (C / 2));
            uint2 u0;
            u0.x = h2pack(acc[j][0].x, acc[j][0].y);
            u0.y = h2pack(acc[j][0].z, acc[j][0].w);
            *(uint2*)(Hb + cg * 2) = u0;
            if constexpr (NB == 2) {
                uint2 u1;
                u1.x = h2pack(acc[j][1].x, acc[j][1].y);
                u1.y = h2pack(acc[j][1].z, acc[j][1].w);
                *(uint2*)(Hb + 32 + cg * 2) = u1;
            }
        }
        float ps = acc[j][0].x * as0.x + acc[j][0].y * as0.y +
                   acc[j][0].z * as0.z + acc[j][0].w * as0.w;
        if constexpr (NB == 2)
            ps += acc[j][1].x * as1.x + acc[j][1].y * as1.y +
                  acc[j][1].z * as1.z + acc[j][1].w * as1.w;
#pragma unroll
        for (int o = 8; o; o >>= 1) ps += __shfl_xor(ps, o, 64);
        if (cg == 0 && ok) { aS[gr] = ps; aD[gr] = pd[j]; }
    }
}

// One wave per destination node: segment softmax + weighted aggregation.
// 4 groups of 16 lanes; group g covers edge j*4+g per step; 4-step unroll
// keeps 16 edges in flight per wave. Rows are f16; MACs via perm+dot2.
template <int C, bool RELU, bool NTOUT>
__global__ __launch_bounds__(256) void aggregate_kernel(
    const int* __restrict__ offs, const int* __restrict__ srcs,
    const unsigned* __restrict__ hsrc, const float* __restrict__ aS,
    const float* __restrict__ aD, const float* __restrict__ bias,
    float* __restrict__ out, int n) {
    int node = (int)((blockIdx.x * blockDim.x + threadIdx.x) >> 6);
    int lane = threadIdx.x & 63;
    if (node >= n) return;
    int beg = offs[node], end = offs[node + 1];
    int deg = end - beg;
    float ad = aD[node];
    const int g = lane >> 4;
    const int l = lane & 15;

    constexpr int NA = C / 16;               // accs per lane (8 or 4)
    float acc[NA];
#pragma unroll
    for (int i = 0; i < NA; ++i) acc[i] = 0.f;

    // one 4-step: edges (j..j+3)*4+g ; out-of-range edges weight-masked
    auto quad = [&](float wv, int sj, int cnt, int j) {
        int e0 = (j + 0) * 4 + g, e1 = (j + 1) * 4 + g;
        int e2 = (j + 2) * 4 + g, e3 = (j + 3) * 4 + g;
        float w0 = __shfl(wv, e0, 64), w1 = __shfl(wv, e1, 64);
        float w2 = __shfl(wv, e2, 64), w3 = __shfl(wv, e3, 64);
        int s0 = __shfl(sj, e0, 64), s1 = __shfl(sj, e1, 64);
        int s2 = __shfl(sj, e2, 64), s3 = __shfl(sj, e3, 64);
        if (e0 >= cnt) w0 = 0.f;            // shfl wraps at 64; mask
        if (e1 >= cnt) w1 = 0.f;
        if (e2 >= cnt) w2 = 0.f;
        if (e3 >= cnt) w3 = 0.f;
        v2h w01, w23;
        w01.x = (_Float16)w0; w01.y = (_Float16)w1;
        w23.x = (_Float16)w2; w23.y = (_Float16)w3;
        if constexpr (C == 128) {
            uint4 a = ((const uint4*)(hsrc + ((size_t)s0 << 6)))[l];
            uint4 b = ((const uint4*)(hsrc + ((size_t)s1 << 6)))[l];
            uint4 c = ((const uint4*)(hsrc + ((size_t)s2 << 6)))[l];
            uint4 d = ((const uint4*)(hsrc + ((size_t)s3 << 6)))[l];
            const unsigned* au = (const unsigned*)&a;
            const unsigned* bu = (const unsigned*)&b;
            const unsigned* cu = (const unsigned*)&c;
            const unsigned* du = (const unsigned*)&d;
#pragma unroll
            for (int i = 0; i < 4; ++i) {
                acc[2 * i] = fdot2u(__builtin_amdgcn_perm(au[i], bu[i], SEL_LO), w01,
                             fdot2u(__builtin_amdgcn_perm(cu[i], du[i], SEL_LO), w23, acc[2 * i]));
                acc[2 * i + 1] = fdot2u(__builtin_amdgcn_perm(au[i], bu[i], SEL_HI), w01,
                                 fdot2u(__builtin_amdgcn_perm(cu[i], du[i], SEL_HI), w23, acc[2 * i + 1]));
            }
        } else {
            uint2 a = ((const uint2*)(hsrc + ((size_t)s0 << 5)))[l];
            uint2 b = ((const uint2*)(hsrc + ((size_t)s1 << 5)))[l];
            uint2 c = ((const uint2*)(hsrc + ((size_t)s2 << 5)))[l];
            uint2 d = ((const uint2*)(hsrc + ((size_t)s3 << 5)))[l];
            const unsigned* au = (const unsigned*)&a;
            const unsigned* bu = (const unsigned*)&b;
            const unsigned* cu = (const unsigned*)&c;
            const unsigned* du = (const unsigned*)&d;
#pragma unroll
            for (int i = 0; i < 2; ++i) {
                acc[2 * i] = fdot2u(__builtin_amdgcn_perm(au[i], bu[i], SEL_LO), w01,
                             fdot2u(__builtin_amdgcn_perm(cu[i], du[i], SEL_LO), w23, acc[2 * i]));
                acc[2 * i + 1] = fdot2u(__builtin_amdgcn_perm(au[i], bu[i], SEL_HI), w01,
                                 fdot2u(__builtin_amdgcn_perm(cu[i], du[i], SEL_HI), w23, acc[2 * i + 1]));
            }
        }
    };

    if (deg <= 64) {
        int i = beg + lane;
        int sj = 0;
        float lv = -INFINITY;
        if (i < end) {
            sj = __builtin_nontemporal_load(srcs + i);
            float lg = aS[sj] + ad;
            lv = (lg > 0.f) ? lg : 0.2f * lg;
        }
        float m = lv;
#pragma unroll
        for (int o = 32; o; o >>= 1) m = fmaxf(m, __shfl_xor(m, o, 64));
        float e = (i < end) ? __expf(lv - m) : 0.f;
        float s = e;
#pragma unroll
        for (int o = 32; o; o >>= 1) s += __shfl_xor(s, o, 64);
        float w = e * (1.f / (s + 1e-16f));
        int jm = (deg + 3) >> 2;
        for (int j = 0; j < jm; j += 4) quad(w, sj, deg, j);
    } else {
        float m = -INFINITY;
        for (int i = beg + lane; i < end; i += 64) {
            float lg = aS[srcs[i]] + ad;
            lg = (lg > 0.f) ? lg : 0.2f * lg;
            m = fmaxf(m, lg);
        }
#pragma unroll
        for (int o = 32; o; o >>= 1) m = fmaxf(m, __shfl_xor(m, o, 64));
        float s = 0.f;
        for (int i = beg + lane; i < end; i += 64) {
            float lg = aS[srcs[i]] + ad;
            lg = (lg > 0.f) ? lg : 0.2f * lg;
            s += __expf(lg - m);
        }
#pragma unroll
        for (int o = 32; o; o >>= 1) s += __shfl_xor(s, o, 64);
        float inv = 1.f / (s + 1e-16f);
        for (int base = beg; base < end; base += 64) {
            int i = base + lane;
            int sj = 0;
            float w = 0.f;
            if (i < end) {
                sj = srcs[i];
                float lg = aS[sj] + ad;
                lg = (lg > 0.f) ? lg : 0.2f * lg;
                w = __expf(lg - m) * inv;
            }
            int cnt = min(64, end - base);
            int jm = (cnt + 3) >> 2;
            for (int j = 0; j < jm; j += 4) quad(w, sj, cnt, j);
        }
    }

    // cross-group reduce over lane bits 4..5
#pragma unroll
    for (int i = 0; i < NA; ++i) {
        acc[i] += __shfl_xor(acc[i], 16, 64);
        acc[i] += __shfl_xor(acc[i], 32, 64);
    }

    if (lane < 16) {
        constexpr int PC = NA / 4;         // float4s per lane (2 or 1)
        int c0 = lane * NA;
        float* op = out + (size_t)node * C + c0;
        const float* bp = bias + c0;
#pragma unroll
        for (int q = 0; q < PC; ++q) {
            v4f b = *(const v4f*)(bp + q * 4);
            v4f o;
            o.x = acc[q * 4 + 0] + b.x;
            o.y = acc[q * 4 + 1] + b.y;
            o.z = acc[q * 4 + 2] + b.z;
            o.w = acc[q * 4 + 3] + b.w;
            if (RELU) {
                o.x = fmaxf(o.x, 0.f); o.y = fmaxf(o.y, 0.f);
                o.z = fmaxf(o.z, 0.f); o.w = fmaxf(o.w, 0.f);
            }
            if (NTOUT) ntstore4(op + q * 4, o);
            else *(v4f*)(op + q * 4) = o;
        }
    }
}

extern "C" void kernel_launch(void* const* d_in, const int* in_sizes, int n_in,
                              void* d_out, int out_size, void* d_ws, size_t ws_size,
                              hipStream_t stream) {
    const float* x     = (const float*)d_in[0];
    const int*   edge  = (const int*)d_in[1];
    const float* W1s   = (const float*)d_in[2];
    const float* W1d   = (const float*)d_in[3];
    const float* att1s = (const float*)d_in[4];
    const float* att1d = (const float*)d_in[5];
    const float* b1    = (const float*)d_in[6];
    const float* W2s   = (const float*)d_in[7];
    const float* W2d   = (const float*)d_in[8];
    const float* att2s = (const float*)d_in[9];
    const float* att2d = (const float*)d_in[10];
    const float* b2    = (const float*)d_in[11];

    const int N = in_sizes[0] / 128;
    const int E = in_sizes[1] / 2;
    const int* srcI = edge;
    const int* dstI = edge + E;

    size_t off = 0;
    auto alloc = [&](size_t bytes) {
        void* p = (char*)d_ws + off;
        off += (bytes + 255) & ~(size_t)255;
        return p;
    };
    int*      offs  = (int*)alloc((size_t)(N + 1) * 4);
    int*      srcs  = (int*)alloc((size_t)E * 4);
    int*      gh    = (int*)alloc(256 * 4);
    int*      bbase = (int*)alloc(257 * 4);
    int*      gcur  = (int*)alloc(256 * 4);
    float*    watt1 = (float*)alloc(128 * 4);
    float*    watt2 = (float*)alloc(128 * 4);
    float*    a_s   = (float*)alloc((size_t)N * 4);
    float*    a_d   = (float*)alloc((size_t)N * 4);
    unsigned* h1h   = (unsigned*)alloc((size_t)N * 128 * 2);  // layer-1 h_src, f16
    float*    h1    = (float*)alloc((size_t)N * 128 * 4);     // relu(layer1 out), f32
    unsigned* h2h   = (unsigned*)alloc((size_t)N * 64 * 2);   // layer-2 h_src, f16
    u64*      pairs = (u64*)h1;   // dead until agg128 writes h1 (bsort << agg128)

    hipMemsetAsync(gh, 0, 256 * 4, stream);
    matvec_kernel<<<1, 128, 0, stream>>>(W1d, att1d, watt1, 128, 128);
    matvec_kernel<<<1, 128, 0, stream>>>(W2d, att2d, watt2, 128, 64);

    const int nbE = (E + 4095) / 4096;
    const int nbuckets = (N + 511) >> 9;
    bhist_kernel<<<nbE, 256, 0, stream>>>(dstI, gh, E);
    bscan_kernel<<<1, 256, 0, stream>>>(gh, bbase, gcur, offs, N, E);
    bscatter_kernel<<<nbE, 256, 0, stream>>>(srcI, dstI, gcur, pairs, E);
    bsort_kernel<<<nbuckets, 512, 0, stream>>>(pairs, bbase, offs, srcs, N);

    int gblk = (N + 63) / 64;
    gemm_att_kernel<128><<<gblk, 256, 0, stream>>>(x, W1s, att1s, watt1, h1h, a_s, a_d, N);
    aggregate_kernel<128, true, false><<<(N + 3) / 4, 256, 0, stream>>>(
        offs, srcs, h1h, a_s, a_d, b1, h1, N);
    gemm_att_kernel<64><<<gblk, 256, 0, stream>>>(h1, W2s, att2s, watt2, h2h, a_s, a_d, N);
    aggregate_kernel<64, false, true><<<(N + 3) / 4, 256, 0, stream>>>(
        offs, srcs, h2h, a_s, a_d, b2, (float*)d_out, N);
}

// Round 9
// 385.904 us; speedup vs baseline: 1.2380x; 1.0735x over previous
//
#include <hip/hip_runtime.h>

// ---------------------------------------------------------------------------
// GAT 2-layer encoder. N=100k nodes, E=1.6M edges, 128->128(relu)->64.
//   a_dst = x . (W_dst @ att_dst)  (h_dst never materialized)
//   CSR-by-dst via two-level counting sort (write-amp-free)
//   register-tiled fp32 GEMM (4x8 per thread, conflict-free LDS)
//   all intermediate node arrays f16 (gathers AND streams); aggregation
//   inner loop uses v_perm_b32 + v_dot2_f32_f16 (f32 accumulate)
//   fast-path softmax skips the max pass (logits bounded; shift-invariant)
// ---------------------------------------------------------------------------

typedef unsigned long long u64;
typedef float v4f __attribute__((ext_vector_type(4)));
typedef _Float16 v2h __attribute__((ext_vector_type(2)));

#define SEL_LO 0x01000504u   // (a.f16lo, b.f16lo)
#define SEL_HI 0x03020706u   // (a.f16hi, b.f16hi)

__device__ __forceinline__ void ntstore4(float* p, v4f v) {
    __builtin_nontemporal_store(v, (v4f*)p);
}
__device__ __forceinline__ unsigned h2pack(float a, float b) {  // RNE
    v2h h;
    h.x = (_Float16)a;
    h.y = (_Float16)b;
    return __builtin_bit_cast(unsigned, h);
}
__device__ __forceinline__ float h2lo(unsigned u) {
    v2h h = __builtin_bit_cast(v2h, u);
    return (float)h.x;
}
__device__ __forceinline__ float h2hi(unsigned u) {
    v2h h = __builtin_bit_cast(v2h, u);
    return (float)h.y;
}
__device__ __forceinline__ float fdot2u(unsigned u, v2h w, float acc) {
    return __builtin_amdgcn_fdot2(__builtin_bit_cast(v2h, u), w, acc, false);
}
__device__ __forceinline__ v2h pkrtz(float a, float b) {
    return __builtin_bit_cast(v2h, __builtin_amdgcn_cvt_pkrtz(a, b));
}

// one wave per output row
__global__ __launch_bounds__(64) void matvec_kernel(const float* __restrict__ W,
                                                    const float* __restrict__ a,
                                                    float* __restrict__ out, int cols) {
    int row = blockIdx.x;
    int lane = threadIdx.x;
    float s = 0.f;
    for (int j = lane; j < cols; j += 64) s += W[row * cols + j] * a[j];
#pragma unroll
    for (int o = 32; o; o >>= 1) s += __shfl_xor(s, o, 64);
    if (lane == 0) out[row] = s;
}

// ---- CSR build: two-level counting sort ----
__global__ __launch_bounds__(256) void bhist_kernel(const int* __restrict__ dst,
                                                    int* __restrict__ gh, int E) {
    __shared__ int h[256];
    h[threadIdx.x] = 0;
    __syncthreads();
    int base = blockIdx.x * 4096;
    int lim = min(base + 4096, E);
    for (int i = base + threadIdx.x; i < lim; i += 256)
        atomicAdd(&h[__builtin_nontemporal_load(dst + i) >> 9], 1);
    __syncthreads();
    int v = h[threadIdx.x];
    if (v) atomicAdd(&gh[threadIdx.x], v);
}

__global__ __launch_bounds__(256) void bscan_kernel(const int* __restrict__ gh,
                                                    int* __restrict__ bbase,
                                                    int* __restrict__ gcur,
                                                    int* __restrict__ offs, int N, int E) {
    __shared__ int s[256];
    int t = threadIdx.x;
    int v = gh[t];
    s[t] = v;
    __syncthreads();
    for (int o = 1; o < 256; o <<= 1) {
        int u = (t >= o) ? s[t - o] : 0;
        __syncthreads();
        s[t] += u;
        __syncthreads();
    }
    int excl = s[t] - v;
    bbase[t] = excl;
    gcur[t] = excl;
    if (t == 255) { bbase[256] = E; offs[N] = E; }
}

__global__ __launch_bounds__(256) void bscatter_kernel(const int* __restrict__ src,
                                                       const int* __restrict__ dst,
                                                       int* __restrict__ gcur,
                                                       u64* __restrict__ pairs, int E) {
    __shared__ int h[256];
    __shared__ int rbase[256];
    const int tid = threadIdx.x;
    h[tid] = 0;
    __syncthreads();
    const int base = blockIdx.x * 4096;
    u64 pv[16];
    int rk[16];
    int bk[16];
#pragma unroll 16
    for (int k = 0; k < 16; ++k) {
        int i = base + k * 256 + tid;
        if (i < E) {
            int d = __builtin_nontemporal_load(dst + i);
            int b = d >> 9;
            bk[k] = b;
            pv[k] = ((u64)(unsigned)d << 32) | (unsigned)__builtin_nontemporal_load(src + i);
            rk[k] = atomicAdd(&h[b], 1);
        } else {
            bk[k] = -1;
        }
    }
    __syncthreads();
    int c = h[tid];
    rbase[tid] = c ? atomicAdd(&gcur[tid], c) : 0;
    __syncthreads();
#pragma unroll 16
    for (int k = 0; k < 16; ++k)
        if (bk[k] >= 0)
            __builtin_nontemporal_store(pv[k], pairs + (size_t)rbase[bk[k]] + rk[k]);
}

__global__ __launch_bounds__(512) void bsort_kernel(const u64* __restrict__ pairs,
                                                    const int* __restrict__ bbase,
                                                    int* __restrict__ offs,
                                                    int* __restrict__ srcs, int N) {
    __shared__ int h[512];
    __shared__ int cur[512];
    const int t = threadIdx.x;
    const int b = blockIdx.x;
    const int beg = bbase[b], end = bbase[b + 1];
    h[t] = 0;
    __syncthreads();
    for (int i = beg + t; i < end; i += 512)
        atomicAdd(&h[(int)(__builtin_nontemporal_load(pairs + i) >> 32) & 511], 1);
    __syncthreads();
    int v = h[t];
    cur[t] = v;
    __syncthreads();
    for (int o = 1; o < 512; o <<= 1) {
        int u = (t >= o) ? cur[t - o] : 0;
        __syncthreads();
        cur[t] += u;
        __syncthreads();
    }
    int pos0 = beg + cur[t] - v;
    __syncthreads();
    cur[t] = pos0;
    int g = (b << 9) + t;
    if (g < N) offs[g] = pos0;
    __syncthreads();
    for (int i = beg + t; i < end; i += 512) {
        u64 p = __builtin_nontemporal_load(pairs + i);
        int local = (int)(p >> 32) & 511;
        int pp = atomicAdd(&cur[local], 1);
        srcs[pp] = (int)(p & 0xffffffffu);
    }
}

// H = X @ W  (X:[M,128] f32 or f16, W:[128,C]); H stored packed f16.
// Fused epilogue: aS[m] = H[m,:] . attS ; aD[m] = X[m,:] . wda
template <int C, bool XF16>
__global__ __launch_bounds__(256) void gemm_att_kernel(
    const void* __restrict__ Xv, const float* __restrict__ W,
    const float* __restrict__ attS, const float* __restrict__ wda,
    unsigned* __restrict__ H, float* __restrict__ aS, float* __restrict__ aD, int M) {
    constexpr int NB = (C == 128) ? 2 : 1;
    __shared__ float4 Xs[16 * 65];          // [k4][row], coeff 65 rotates banks
    __shared__ float  Ws[64 * C];           // k-major half of W

    const int t  = threadIdx.x;
    const int m0 = blockIdx.x * 64;
    const int rg = t >> 4;                  // 0..15 row group
    const int cg = t & 15;                  // 0..15 col group

    float4 acc[4][NB];
#pragma unroll
    for (int j = 0; j < 4; ++j)
#pragma unroll
        for (int b = 0; b < NB; ++b) acc[j][b] = make_float4(0.f, 0.f, 0.f, 0.f);
    float pd[4] = {0.f, 0.f, 0.f, 0.f};

    for (int kk = 0; kk < 128; kk += 64) {
        {
            const float4* Wg = (const float4*)(W + (size_t)kk * C);
            float4* WsV = (float4*)Ws;
#pragma unroll
            for (int i = 0; i < C / 16; ++i) WsV[i * 256 + t] = Wg[i * 256 + t];
        }
#pragma unroll
        for (int i = 0; i < 4; ++i) {
            int f4 = i * 256 + t;
            int row = f4 >> 4;
            int k4 = f4 & 15;
            int gr = m0 + row;
            float4 v = make_float4(0.f, 0.f, 0.f, 0.f);
            if (gr < M) {
                if constexpr (XF16) {
                    const unsigned* Xu = (const unsigned*)Xv + ((size_t)gr << 6);
                    uint2 u = *(const uint2*)(Xu + (kk >> 1) + k4 * 2);
                    v = make_float4(h2lo(u.x), h2hi(u.x), h2lo(u.y), h2hi(u.y));
                } else {
                    v = *(const float4*)((const float*)Xv + (size_t)gr * 128 + kk + k4 * 4);
                }
            }
            Xs[k4 * 65 + row] = v;
        }
        __syncthreads();

#pragma unroll 4
        for (int k4 = 0; k4 < 16; ++k4) {
            float4 a[4];
#pragma unroll
            for (int j = 0; j < 4; ++j) a[j] = Xs[k4 * 65 + rg * 4 + j];
            const float* wrow = Ws + k4 * 4 * C;
            const float* wd = wda + kk + k4 * 4;
#pragma unroll
            for (int u = 0; u < 4; ++u) {
                float4 b0 = *(const float4*)(wrow + u * C + cg * 4);
                float wdu = wd[u];
                float av[4];
#pragma unroll
                for (int j = 0; j < 4; ++j) av[j] = ((const float*)&a[j])[u];
#pragma unroll
                for (int j = 0; j < 4; ++j) {
                    acc[j][0].x += av[j] * b0.x;
                    acc[j][0].y += av[j] * b0.y;
                    acc[j][0].z += av[j] * b0.z;
                    acc[j][0].w += av[j] * b0.w;
                    pd[j] += av[j] * wdu;
                }
                if constexpr (NB == 2) {
                    float4 b1 = *(const float4*)(wrow + u * C + 64 + cg * 4);
#pragma unroll
                    for (int j = 0; j < 4; ++j) {
                        acc[j][1].x += av[j] * b1.x;
                        acc[j][1].y += av[j] * b1.y;
                        acc[j][1].z += av[j] * b1.z;
                        acc[j][1].w += av[j] * b1.w;
                    }
                }
            }
        }
        __syncthreads();
    }

    float4 as0 = *(const float4*)(attS + cg * 4);
    float4 as1 = make_float4(0.f, 0.f, 0.f, 0.f);
    if constexpr (NB == 2) as1 = *(const float4*)(attS + 64 + cg * 4);
#pragma unroll
    for (int j = 0; j < 4; ++j) {
        int gr = m0 + rg * 4 + j;
        bool ok = gr < M;
        if (ok) {
            unsigned* Hb = H + ((size_t)gr * (C / 2));
            uint2 u0;
            u0.x = h2pack(acc[j][0].x, acc[j][0].y);
            u0.y = h2pack(acc[j][0].z, acc[j][0].w);
            *(uint2*)(Hb + cg * 2) = u0;
            if constexpr (NB == 2) {
                uint2 u1;
                u1.x = h2pack(acc[j][1].x, acc[j][1].y);
                u1.y = h2pack(acc[j][1].z, acc[j][1].w);
                *(uint2*)(Hb + 32 + cg * 2) = u1;
            }
        }
        float ps = acc[j][0].x * as0.x + acc[j][0].y * as0.y +
                   acc[j][0].z * as0.z + acc[j][0].w * as0.w;
        if constexpr (NB == 2)
            ps += acc[j][1].x * as1.x + acc[j][1].y * as1.y +
                  acc[j][1].z * as1.z + acc[j][1].w * as1.w;
#pragma unroll
        for (int o = 8; o; o >>= 1) ps += __shfl_xor(ps, o, 64);
        if (cg == 0 && ok) { aS[gr] = ps; aD[gr] = pd[j]; }
    }
}

// One wave per destination node: segment softmax + weighted aggregation.
// 4 groups of 16 lanes; group g covers edges e == g (mod 4); 4-step unroll
// keeps 16 edges in flight per wave. Rows f16; MACs via perm+dot2.
// Invalid edge slots carry w == 0 (no masks needed; e <= 63 so no shfl wrap).
template <int C, bool RELU, bool F16OUT, bool NTOUT>
__global__ __launch_bounds__(256) void aggregate_kernel(
    const int* __restrict__ offs, const int* __restrict__ srcs,
    const unsigned* __restrict__ hsrc, const float* __restrict__ aS,
    const float* __restrict__ aD, const float* __restrict__ bias,
    void* __restrict__ outv, int n) {
    int node = (int)((blockIdx.x * blockDim.x + threadIdx.x) >> 6);
    int lane = threadIdx.x & 63;
    if (node >= n) return;
    int beg = offs[node], end = offs[node + 1];
    int deg = end - beg;
    float ad = aD[node];
    const int g = lane >> 4;
    const int l = lane & 15;

    constexpr int NA = C / 16;               // accs per lane (8 or 4)
    float acc[NA];
#pragma unroll
    for (int i = 0; i < NA; ++i) acc[i] = 0.f;

    auto quad = [&](float wv, int sj, int j) {
        int e0 = (j + 0) * 4 + g, e1 = (j + 1) * 4 + g;
        int e2 = (j + 2) * 4 + g, e3 = (j + 3) * 4 + g;
        float w0 = __shfl(wv, e0, 64), w1 = __shfl(wv, e1, 64);
        float w2 = __shfl(wv, e2, 64), w3 = __shfl(wv, e3, 64);
        int s0 = __shfl(sj, e0, 64), s1 = __shfl(sj, e1, 64);
        int s2 = __shfl(sj, e2, 64), s3 = __shfl(sj, e3, 64);
        v2h w01 = pkrtz(w0, w1);
        v2h w23 = pkrtz(w2, w3);
        if constexpr (C == 128) {
            uint4 a = ((const uint4*)(hsrc + ((size_t)s0 << 6)))[l];
            uint4 b = ((const uint4*)(hsrc + ((size_t)s1 << 6)))[l];
            uint4 c = ((const uint4*)(hsrc + ((size_t)s2 << 6)))[l];
            uint4 d = ((const uint4*)(hsrc + ((size_t)s3 << 6)))[l];
            const unsigned* au = (const unsigned*)&a;
            const unsigned* bu = (const unsigned*)&b;
            const unsigned* cu = (const unsigned*)&c;
            const unsigned* du = (const unsigned*)&d;
#pragma unroll
            for (int i = 0; i < 4; ++i) {
                acc[2 * i] = fdot2u(__builtin_amdgcn_perm(au[i], bu[i], SEL_LO), w01,
                             fdot2u(__builtin_amdgcn_perm(cu[i], du[i], SEL_LO), w23, acc[2 * i]));
                acc[2 * i + 1] = fdot2u(__builtin_amdgcn_perm(au[i], bu[i], SEL_HI), w01,
                                 fdot2u(__builtin_amdgcn_perm(cu[i], du[i], SEL_HI), w23, acc[2 * i + 1]));
            }
        } else {
            uint2 a = ((const uint2*)(hsrc + ((size_t)s0 << 5)))[l];
            uint2 b = ((const uint2*)(hsrc + ((size_t)s1 << 5)))[l];
            uint2 c = ((const uint2*)(hsrc + ((size_t)s2 << 5)))[l];
            uint2 d = ((const uint2*)(hsrc + ((size_t)s3 << 5)))[l];
            const unsigned* au = (const unsigned*)&a;
            const unsigned* bu = (const unsigned*)&b;
            const unsigned* cu = (const unsigned*)&c;
            const unsigned* du = (const unsigned*)&d;
#pragma unroll
            for (int i = 0; i < 2; ++i) {
                acc[2 * i] = fdot2u(__builtin_amdgcn_perm(au[i], bu[i], SEL_LO), w01,
                             fdot2u(__builtin_amdgcn_perm(cu[i], du[i], SEL_LO), w23, acc[2 * i]));
                acc[2 * i + 1] = fdot2u(__builtin_amdgcn_perm(au[i], bu[i], SEL_HI), w01,
                                 fdot2u(__builtin_amdgcn_perm(cu[i], du[i], SEL_HI), w23, acc[2 * i + 1]));
            }
        }
    };

    if (deg <= 64) {
        // fast path: softmax without max-shift (logits bounded; shift-invariant)
        int i = beg + lane;
        int sj = 0;
        float w = 0.f;
        if (i < end) {
            sj = __builtin_nontemporal_load(srcs + i);
            float lg = aS[sj] + ad;
            lg = (lg > 0.f) ? lg : 0.2f * lg;
            w = __expf(lg);
        }
        float s = w;
#pragma unroll
        for (int o = 32; o; o >>= 1) s += __shfl_xor(s, o, 64);
        w *= 1.f / (s + 1e-16f);
        int jm = (deg + 3) >> 2;
        for (int j = 0; j < jm; j += 4) quad(w, sj, j);
    } else {
        float m = -INFINITY;
        for (int i = beg + lane; i < end; i += 64) {
            float lg = aS[srcs[i]] + ad;
            lg = (lg > 0.f) ? lg : 0.2f * lg;
            m = fmaxf(m, lg);
        }
#pragma unroll
        for (int o = 32; o; o >>= 1) m = fmaxf(m, __shfl_xor(m, o, 64));
        float s = 0.f;
        for (int i = beg + lane; i < end; i += 64) {
            float lg = aS[srcs[i]] + ad;
            lg = (lg > 0.f) ? lg : 0.2f * lg;
            s += __expf(lg - m);
        }
#pragma unroll
        for (int o = 32; o; o >>= 1) s += __shfl_xor(s, o, 64);
        float inv = 1.f / (s + 1e-16f);
        for (int base = beg; base < end; base += 64) {
            int i = base + lane;
            int sj = 0;
            float w = 0.f;
            if (i < end) {
                sj = srcs[i];
                float lg = aS[sj] + ad;
                lg = (lg > 0.f) ? lg : 0.2f * lg;
                w = __expf(lg - m) * inv;
            }
            int cnt = min(64, end - base);
            int jm = (cnt + 3) >> 2;
            for (int j = 0; j < jm; j += 4) quad(w, sj, j);
        }
    }

    // cross-group reduce over lane bits 4..5
#pragma unroll
    for (int i = 0; i < NA; ++i) {
        acc[i] += __shfl_xor(acc[i], 16, 64);
        acc[i] += __shfl_xor(acc[i], 32, 64);
    }

    if (lane < 16) {
        float o[NA];
        const float* bp = bias + lane * NA;
#pragma unroll
        for (int i = 0; i < NA; ++i) {
            o[i] = acc[i] + bp[i];
            if (RELU) o[i] = fmaxf(o[i], 0.f);
        }
        if constexpr (F16OUT) {
            unsigned u[NA / 2];
#pragma unroll
            for (int k = 0; k < NA / 2; ++k) u[k] = h2pack(o[2 * k], o[2 * k + 1]);
            unsigned* op = (unsigned*)outv + (size_t)node * (C / 2) + lane * (NA / 2);
            if constexpr (NA == 8) *(uint4*)op = make_uint4(u[0], u[1], u[2], u[3]);
            else *(uint2*)op = make_uint2(u[0], u[1]);
        } else {
            float* op = (float*)outv + (size_t)node * C + lane * NA;
#pragma unroll
            for (int q = 0; q < NA / 4; ++q) {
                v4f ov;
                ov.x = o[q * 4 + 0]; ov.y = o[q * 4 + 1];
                ov.z = o[q * 4 + 2]; ov.w = o[q * 4 + 3];
                if (NTOUT) ntstore4(op + q * 4, ov);
                else *(v4f*)(op + q * 4) = ov;
            }
        }
    }
}

extern "C" void kernel_launch(void* const* d_in, const int* in_sizes, int n_in,
                              void* d_out, int out_size, void* d_ws, size_t ws_size,
                              hipStream_t stream) {
    const float* x     = (const float*)d_in[0];
    const int*   edge  = (const int*)d_in[1];
    const float* W1s   = (const float*)d_in[2];
    const float* W1d   = (const float*)d_in[3];
    const float* att1s = (const float*)d_in[4];
    const float* att1d = (const float*)d_in[5];
    const float* b1    = (const float*)d_in[6];
    const float* W2s   = (const float*)d_in[7];
    const float* W2d   = (const float*)d_in[8];
    const float* att2s = (const float*)d_in[9];
    const float* att2d = (const float*)d_in[10];
    const float* b2    = (const float*)d_in[11];

    const int N = in_sizes[0] / 128;
    const int E = in_sizes[1] / 2;
    const int* srcI = edge;
    const int* dstI = edge + E;

    size_t off = 0;
    auto alloc = [&](size_t bytes) {
        void* p = (char*)d_ws + off;
        off += (bytes + 255) & ~(size_t)255;
        return p;
    };
    int*      offs  = (int*)alloc((size_t)(N + 1) * 4);
    int*      srcs  = (int*)alloc((size_t)E * 4);
    int*      gh    = (int*)alloc(256 * 4);
    int*      bbase = (int*)alloc(257 * 4);
    int*      gcur  = (int*)alloc(256 * 4);
    float*    watt1 = (float*)alloc(128 * 4);
    float*    watt2 = (float*)alloc(128 * 4);
    float*    a_s   = (float*)alloc((size_t)N * 4);
    float*    a_d   = (float*)alloc((size_t)N * 4);
    unsigned* g1h   = (unsigned*)alloc((size_t)N * 128 * 2);  // gemm1 out (gather), f16
    unsigned* h1h   = (unsigned*)alloc((size_t)N * 128 * 2);  // agg1 out / gemm2 in, f16
    unsigned* g2h   = (unsigned*)alloc((size_t)N * 64 * 2);   // gemm2 out (gather), f16
    u64*      pairs = (u64*)h1h;   // dead until agg1 writes h1h (bsort << agg1)

    hipMemsetAsync(gh, 0, 256 * 4, stream);
    matvec_kernel<<<128, 64, 0, stream>>>(W1d, att1d, watt1, 128);
    matvec_kernel<<<128, 64, 0, stream>>>(W2d, att2d, watt2, 64);

    const int nbE = (E + 4095) / 4096;
    const int nbuckets = (N + 511) >> 9;
    bhist_kernel<<<nbE, 256, 0, stream>>>(dstI, gh, E);
    bscan_kernel<<<1, 256, 0, stream>>>(gh, bbase, gcur, offs, N, E);
    bscatter_kernel<<<nbE, 256, 0, stream>>>(srcI, dstI, gcur, pairs, E);
    bsort_kernel<<<nbuckets, 512, 0, stream>>>(pairs, bbase, offs, srcs, N);

    int gblk = (N + 63) / 64;
    gemm_att_kernel<128, false><<<gblk, 256, 0, stream>>>(x, W1s, att1s, watt1, g1h, a_s, a_d, N);
    aggregate_kernel<128, true, true, false><<<(N + 3) / 4, 256, 0, stream>>>(
        offs, srcs, g1h, a_s, a_d, b1, h1h, N);
    gemm_att_kernel<64, true><<<gblk, 256, 0, stream>>>(h1h, W2s, att2s, watt2, g2h, a_s, a_d, N);
    aggregate_kernel<64, false, false, true><<<(N + 3) / 4, 256, 0, stream>>>(
        offs, srcs, g2h, a_s, a_d, b2, d_out, N);
}

// Round 10
// 335.438 us; speedup vs baseline: 1.4242x; 1.1504x over previous
//
#include <hip/hip_runtime.h>

// ---------------------------------------------------------------------------
// GAT 2-layer encoder. N=100k nodes, E=1.6M edges, 128->128(relu)->64.
//   a_dst = x . (W_dst @ att_dst)  (h_dst never materialized)
//   CSR-by-dst via two-level counting sort (write-amp-free)
//   MFMA f16 GEMM (16x16x32), W pre-packed to fragment layout, fused aS/aD
//   all intermediate node arrays f16; aggregation inner loop uses
//   v_perm_b32 + v_dot2_f32_f16 (f32 accumulate)
// ---------------------------------------------------------------------------

typedef unsigned long long u64;
typedef float v4f __attribute__((ext_vector_type(4)));
typedef _Float16 v2h __attribute__((ext_vector_type(2)));
typedef __fp16 h8 __attribute__((ext_vector_type(8)));

#define SEL_LO 0x01000504u   // (a.f16lo, b.f16lo)
#define SEL_HI 0x03020706u   // (a.f16hi, b.f16hi)

__device__ __forceinline__ void ntstore4(float* p, v4f v) {
    __builtin_nontemporal_store(v, (v4f*)p);
}
__device__ __forceinline__ unsigned h2pack(float a, float b) {  // RNE
    v2h h;
    h.x = (_Float16)a;
    h.y = (_Float16)b;
    return __builtin_bit_cast(unsigned, h);
}
__device__ __forceinline__ float fdot2u(unsigned u, v2h w, float acc) {
    return __builtin_amdgcn_fdot2(__builtin_bit_cast(v2h, u), w, acc, false);
}
__device__ __forceinline__ v2h pkrtz(float a, float b) {
    return __builtin_bit_cast(v2h, __builtin_amdgcn_cvt_pkrtz(a, b));
}

// one wave per output row
__global__ __launch_bounds__(64) void matvec_kernel(const float* __restrict__ W,
                                                    const float* __restrict__ a,
                                                    float* __restrict__ out, int cols) {
    int row = blockIdx.x;
    int lane = threadIdx.x;
    float s = 0.f;
    for (int j = lane; j < cols; j += 64) s += W[row * cols + j] * a[j];
#pragma unroll
    for (int o = 32; o; o >>= 1) s += __shfl_xor(s, o, 64);
    if (lane == 0) out[row] = s;
}

// pack W [128 x C] f32 -> MFMA B-fragment order, f16:
//   Wp[(t*NT + tile)*64 + lane] = 8 f16 { W[32t+(lane>>4)*8+j][tile*16+(lane&15)] }
template <int C>
__global__ __launch_bounds__(256) void packw_kernel(const float* __restrict__ W,
                                                    uint4* __restrict__ Wp) {
    constexpr int NT = C / 16;
    const int total = 4 * NT * 64;
    for (int e = threadIdx.x; e < total; e += 256) {
        int lane = e & 63;
        int ti = (e >> 6) % NT;
        int t = (e >> 6) / NT;
        int k0 = 32 * t + (lane >> 4) * 8;
        int n = ti * 16 + (lane & 15);
        unsigned u[4];
#pragma unroll
        for (int p = 0; p < 4; ++p)
            u[p] = h2pack(W[(size_t)(k0 + 2 * p) * C + n], W[(size_t)(k0 + 2 * p + 1) * C + n]);
        Wp[e] = make_uint4(u[0], u[1], u[2], u[3]);
    }
}

// ---- CSR build: two-level counting sort ----
__global__ __launch_bounds__(256) void bhist_kernel(const int* __restrict__ dst,
                                                    int* __restrict__ gh, int E) {
    __shared__ int h[256];
    h[threadIdx.x] = 0;
    __syncthreads();
    int base = blockIdx.x * 4096;
    int lim = min(base + 4096, E);
    for (int i = base + threadIdx.x; i < lim; i += 256)
        atomicAdd(&h[__builtin_nontemporal_load(dst + i) >> 9], 1);
    __syncthreads();
    int v = h[threadIdx.x];
    if (v) atomicAdd(&gh[threadIdx.x], v);
}

__global__ __launch_bounds__(256) void bscan_kernel(const int* __restrict__ gh,
                                                    int* __restrict__ bbase,
                                                    int* __restrict__ gcur,
                                                    int* __restrict__ offs, int N, int E) {
    __shared__ int s[256];
    int t = threadIdx.x;
    int v = gh[t];
    s[t] = v;
    __syncthreads();
    for (int o = 1; o < 256; o <<= 1) {
        int u = (t >= o) ? s[t - o] : 0;
        __syncthreads();
        s[t] += u;
        __syncthreads();
    }
    int excl = s[t] - v;
    bbase[t] = excl;
    gcur[t] = excl;
    if (t == 255) { bbase[256] = E; offs[N] = E; }
}

__global__ __launch_bounds__(256) void bscatter_kernel(const int* __restrict__ src,
                                                       const int* __restrict__ dst,
                                                       int* __restrict__ gcur,
                                                       u64* __restrict__ pairs, int E) {
    __shared__ int h[256];
    __shared__ int rbase[256];
    const int tid = threadIdx.x;
    h[tid] = 0;
    __syncthreads();
    const int base = blockIdx.x * 4096;
    u64 pv[16];
    int rk[16];
    int bk[16];
#pragma unroll 16
    for (int k = 0; k < 16; ++k) {
        int i = base + k * 256 + tid;
        if (i < E) {
            int d = __builtin_nontemporal_load(dst + i);
            int b = d >> 9;
            bk[k] = b;
            pv[k] = ((u64)(unsigned)d << 32) | (unsigned)__builtin_nontemporal_load(src + i);
            rk[k] = atomicAdd(&h[b], 1);
        } else {
            bk[k] = -1;
        }
    }
    __syncthreads();
    int c = h[tid];
    rbase[tid] = c ? atomicAdd(&gcur[tid], c) : 0;
    __syncthreads();
#pragma unroll 16
    for (int k = 0; k < 16; ++k)
        if (bk[k] >= 0)
            __builtin_nontemporal_store(pv[k], pairs + (size_t)rbase[bk[k]] + rk[k]);
}

__global__ __launch_bounds__(512) void bsort_kernel(const u64* __restrict__ pairs,
                                                    const int* __restrict__ bbase,
                                                    int* __restrict__ offs,
                                                    int* __restrict__ srcs, int N) {
    __shared__ int h[512];
    __shared__ int cur[512];
    const int t = threadIdx.x;
    const int b = blockIdx.x;
    const int beg = bbase[b], end = bbase[b + 1];
    h[t] = 0;
    __syncthreads();
    for (int i = beg + t; i < end; i += 512)
        atomicAdd(&h[(int)(__builtin_nontemporal_load(pairs + i) >> 32) & 511], 1);
    __syncthreads();
    int v = h[t];
    cur[t] = v;
    __syncthreads();
    for (int o = 1; o < 512; o <<= 1) {
        int u = (t >= o) ? cur[t - o] : 0;
        __syncthreads();
        cur[t] += u;
        __syncthreads();
    }
    int pos0 = beg + cur[t] - v;
    __syncthreads();
    cur[t] = pos0;
    int g = (b << 9) + t;
    if (g < N) offs[g] = pos0;
    __syncthreads();
    for (int i = beg + t; i < end; i += 512) {
        u64 p = __builtin_nontemporal_load(pairs + i);
        int local = (int)(p >> 32) & 511;
        int pp = atomicAdd(&cur[local], 1);
        srcs[pp] = (int)(p & 0xffffffffu);
    }
}

// MFMA GEMM: H[M,C] (f16) = X[M,128] @ W; fused aS = H.attS, aD = X.wda.
// One wave per 16-row strip; B-frags from pre-packed Wp (L2-resident).
// Layouts (m89-verified): A[m=lane&15][k=quad*8+j]; B[k=quad*8+j][n=lane&15];
// D col=lane&15, row=quad*4+reg.
template <int C, bool XF16>
__global__ __launch_bounds__(256) void gemm_att_kernel(
    const void* __restrict__ Xv, const uint4* __restrict__ Wp,
    const float* __restrict__ attS, const float* __restrict__ wda,
    unsigned* __restrict__ H, float* __restrict__ aS, float* __restrict__ aD, int M) {
    constexpr int NT = C / 16;
    __shared__ _Float16 hs[4][16 * 136];    // per-wave transpose buffer (pad 136)

    const int tid = threadIdx.x;
    const int w = tid >> 6;
    const int lane = tid & 63;
    const int l15 = lane & 15;
    const int q = lane >> 4;
    const int mb = blockIdx.x * 64 + w * 16;
    const int m = mb + l15;
    const bool mv = m < M;

    v4f acc[NT];
#pragma unroll
    for (int n = 0; n < NT; ++n) acc[n] = (v4f)(0.f);
    float pd = 0.f;
    uint4 afu[4];

    if constexpr (XF16) {
        const uint4* Xp = (const uint4*)Xv + (size_t)m * 16;   // 128 f16 = 16 uint4
#pragma unroll
        for (int t = 0; t < 4; ++t) {
            uint4 u = make_uint4(0u, 0u, 0u, 0u);
            if (mv) u = Xp[4 * t + q];
            afu[t] = u;
            const float* wdp = wda + 32 * t + 8 * q;
            pd = fdot2u(u.x, pkrtz(wdp[0], wdp[1]), pd);
            pd = fdot2u(u.y, pkrtz(wdp[2], wdp[3]), pd);
            pd = fdot2u(u.z, pkrtz(wdp[4], wdp[5]), pd);
            pd = fdot2u(u.w, pkrtz(wdp[6], wdp[7]), pd);
        }
    } else {
        const float* Xp = (const float*)Xv + (size_t)m * 128;
#pragma unroll
        for (int t = 0; t < 4; ++t) {
            float4 x0 = make_float4(0.f, 0.f, 0.f, 0.f);
            float4 x1 = x0;
            if (mv) {
                x0 = *(const float4*)(Xp + 32 * t + 8 * q);
                x1 = *(const float4*)(Xp + 32 * t + 8 * q + 4);
            }
            const float* wdp = wda + 32 * t + 8 * q;
            pd += x0.x * wdp[0] + x0.y * wdp[1] + x0.z * wdp[2] + x0.w * wdp[3] +
                  x1.x * wdp[4] + x1.y * wdp[5] + x1.z * wdp[6] + x1.w * wdp[7];
            afu[t] = make_uint4(h2pack(x0.x, x0.y), h2pack(x0.z, x0.w),
                                h2pack(x1.x, x1.y), h2pack(x1.z, x1.w));
        }
    }

    // MFMA main loop
#pragma unroll
    for (int t = 0; t < 4; ++t) {
        h8 a = __builtin_bit_cast(h8, afu[t]);
        const uint4* wp = Wp + (size_t)t * NT * 64 + lane;
#pragma unroll
        for (int n = 0; n < NT; ++n) {
            h8 b = __builtin_bit_cast(h8, wp[n * 64]);
            acc[n] = __builtin_amdgcn_mfma_f32_16x16x32_f16(a, b, acc[n], 0, 0, 0);
        }
    }

    // aD: reduce per-lane partial over quads (lanes sharing m)
    pd += __shfl_xor(pd, 16, 64);
    pd += __shfl_xor(pd, 32, 64);
    if (q == 0 && mv) aD[m] = pd;

    // aS: dot accumulators with attS, reduce across the 16 cols (same quad)
    float as4[4] = {0.f, 0.f, 0.f, 0.f};
#pragma unroll
    for (int n = 0; n < NT; ++n) {
        float av = attS[n * 16 + l15];
#pragma unroll
        for (int r = 0; r < 4; ++r) as4[r] += acc[n][r] * av;
    }
#pragma unroll
    for (int r = 0; r < 4; ++r) {
#pragma unroll
        for (int o = 1; o < 16; o <<= 1) as4[r] += __shfl_xor(as4[r], o, 64);
    }
    if (l15 == 0) {
#pragma unroll
        for (int r = 0; r < 4; ++r) {
            int row = mb + q * 4 + r;
            if (row < M) aS[row] = as4[r];
        }
    }

    // H store: f16 via per-wave LDS transpose (wave-local; no barrier needed)
    _Float16* hp = hs[w];
#pragma unroll
    for (int n = 0; n < NT; ++n)
#pragma unroll
        for (int r = 0; r < 4; ++r)
            hp[(q * 4 + r) * 136 + n * 16 + l15] = (_Float16)acc[n][r];

    constexpr int CH = C / 32;              // 64-B chunks per row
    if (lane < 16 * CH) {
        int row = lane / CH;
        int ch = lane % CH;
        const uint4* rp = (const uint4*)(hp + row * 136 + ch * 32);
        uint4 v0 = rp[0], v1 = rp[1], v2 = rp[2], v3 = rp[3];
        int gr = mb + row;
        if (gr < M) {
            uint4* op = (uint4*)(H + (size_t)gr * (C / 2)) + ch * 4;
            op[0] = v0; op[1] = v1; op[2] = v2; op[3] = v3;
        }
    }
}

// One wave per destination node: segment softmax + weighted aggregation.
// 4 groups of 16 lanes; 4-step unroll => 16 edges in flight per wave.
template <int C, bool RELU, bool F16OUT, bool NTOUT>
__global__ __launch_bounds__(256) void aggregate_kernel(
    const int* __restrict__ offs, const int* __restrict__ srcs,
    const unsigned* __restrict__ hsrc, const float* __restrict__ aS,
    const float* __restrict__ aD, const float* __restrict__ bias,
    void* __restrict__ outv, int n) {
    int node = (int)((blockIdx.x * blockDim.x + threadIdx.x) >> 6);
    int lane = threadIdx.x & 63;
    if (node >= n) return;
    int beg = offs[node], end = offs[node + 1];
    int deg = end - beg;
    float ad = aD[node];
    const int g = lane >> 4;
    const int l = lane & 15;

    constexpr int NA = C / 16;               // accs per lane (8 or 4)
    float acc[NA];
#pragma unroll
    for (int i = 0; i < NA; ++i) acc[i] = 0.f;

    auto quad = [&](float wv, int sj, int j) {
        int e0 = (j + 0) * 4 + g, e1 = (j + 1) * 4 + g;
        int e2 = (j + 2) * 4 + g, e3 = (j + 3) * 4 + g;
        float w0 = __shfl(wv, e0, 64), w1 = __shfl(wv, e1, 64);
        float w2 = __shfl(wv, e2, 64), w3 = __shfl(wv, e3, 64);
        int s0 = __shfl(sj, e0, 64), s1 = __shfl(sj, e1, 64);
        int s2 = __shfl(sj, e2, 64), s3 = __shfl(sj, e3, 64);
        v2h w01 = pkrtz(w0, w1);
        v2h w23 = pkrtz(w2, w3);
        if constexpr (C == 128) {
            uint4 a = ((const uint4*)(hsrc + ((size_t)s0 << 6)))[l];
            uint4 b = ((const uint4*)(hsrc + ((size_t)s1 << 6)))[l];
            uint4 c = ((const uint4*)(hsrc + ((size_t)s2 << 6)))[l];
            uint4 d = ((const uint4*)(hsrc + ((size_t)s3 << 6)))[l];
            const unsigned* au = (const unsigned*)&a;
            const unsigned* bu = (const unsigned*)&b;
            const unsigned* cu = (const unsigned*)&c;
            const unsigned* du = (const unsigned*)&d;
#pragma unroll
            for (int i = 0; i < 4; ++i) {
                acc[2 * i] = fdot2u(__builtin_amdgcn_perm(au[i], bu[i], SEL_LO), w01,
                             fdot2u(__builtin_amdgcn_perm(cu[i], du[i], SEL_LO), w23, acc[2 * i]));
                acc[2 * i + 1] = fdot2u(__builtin_amdgcn_perm(au[i], bu[i], SEL_HI), w01,
                                 fdot2u(__builtin_amdgcn_perm(cu[i], du[i], SEL_HI), w23, acc[2 * i + 1]));
            }
        } else {
            uint2 a = ((const uint2*)(hsrc + ((size_t)s0 << 5)))[l];
            uint2 b = ((const uint2*)(hsrc + ((size_t)s1 << 5)))[l];
            uint2 c = ((const uint2*)(hsrc + ((size_t)s2 << 5)))[l];
            uint2 d = ((const uint2*)(hsrc + ((size_t)s3 << 5)))[l];
            const unsigned* au = (const unsigned*)&a;
            const unsigned* bu = (const unsigned*)&b;
            const unsigned* cu = (const unsigned*)&c;
            const unsigned* du = (const unsigned*)&d;
#pragma unroll
            for (int i = 0; i < 2; ++i) {
                acc[2 * i] = fdot2u(__builtin_amdgcn_perm(au[i], bu[i], SEL_LO), w01,
                             fdot2u(__builtin_amdgcn_perm(cu[i], du[i], SEL_LO), w23, acc[2 * i]));
                acc[2 * i + 1] = fdot2u(__builtin_amdgcn_perm(au[i], bu[i], SEL_HI), w01,
                                 fdot2u(__builtin_amdgcn_perm(cu[i], du[i], SEL_HI), w23, acc[2 * i + 1]));
            }
        }
    };

    if (deg <= 64) {
        // fast path: softmax without max-shift (logits bounded; shift-invariant)
        int i = beg + lane;
        int sj = 0;
        float w = 0.f;
        if (i < end) {
            sj = __builtin_nontemporal_load(srcs + i);
            float lg = aS[sj] + ad;
            lg = (lg > 0.f) ? lg : 0.2f * lg;
            w = __expf(lg);
        }
        float s = w;
#pragma unroll
        for (int o = 32; o; o >>= 1) s += __shfl_xor(s, o, 64);
        w *= 1.f / (s + 1e-16f);
        int jm = (deg + 3) >> 2;
        for (int j = 0; j < jm; j += 4) quad(w, sj, j);
    } else {
        float m = -INFINITY;
        for (int i = beg + lane; i < end; i += 64) {
            float lg = aS[srcs[i]] + ad;
            lg = (lg > 0.f) ? lg : 0.2f * lg;
            m = fmaxf(m, lg);
        }
#pragma unroll
        for (int o = 32; o; o >>= 1) m = fmaxf(m, __shfl_xor(m, o, 64));
        float s = 0.f;
        for (int i = beg + lane; i < end; i += 64) {
            float lg = aS[srcs[i]] + ad;
            lg = (lg > 0.f) ? lg : 0.2f * lg;
            s += __expf(lg - m);
        }
#pragma unroll
        for (int o = 32; o; o >>= 1) s += __shfl_xor(s, o, 64);
        float inv = 1.f / (s + 1e-16f);
        for (int base = beg; base < end; base += 64) {
            int i = base + lane;
            int sj = 0;
            float w = 0.f;
            if (i < end) {
                sj = srcs[i];
                float lg = aS[sj] + ad;
                lg = (lg > 0.f) ? lg : 0.2f * lg;
                w = __expf(lg - m) * inv;
            }
            int cnt = min(64, end - base);
            int jm = (cnt + 3) >> 2;
            for (int j = 0; j < jm; j += 4) quad(w, sj, j);
        }
    }

    // cross-group reduce over lane bits 4..5
#pragma unroll
    for (int i = 0; i < NA; ++i) {
        acc[i] += __shfl_xor(acc[i], 16, 64);
        acc[i] += __shfl_xor(acc[i], 32, 64);
    }

    if (lane < 16) {
        float o[NA];
        const float* bp = bias + lane * NA;
#pragma unroll
        for (int i = 0; i < NA; ++i) {
            o[i] = acc[i] + bp[i];
            if (RELU) o[i] = fmaxf(o[i], 0.f);
        }
        if constexpr (F16OUT) {
            unsigned u[NA / 2];
#pragma unroll
            for (int k = 0; k < NA / 2; ++k) u[k] = h2pack(o[2 * k], o[2 * k + 1]);
            unsigned* op = (unsigned*)outv + (size_t)node * (C / 2) + lane * (NA / 2);
            if constexpr (NA == 8) *(uint4*)op = make_uint4(u[0], u[1], u[2], u[3]);
            else *(uint2*)op = make_uint2(u[0], u[1]);
        } else {
            float* op = (float*)outv + (size_t)node * C + lane * NA;
#pragma unroll
            for (int q = 0; q < NA / 4; ++q) {
                v4f ov;
                ov.x = o[q * 4 + 0]; ov.y = o[q * 4 + 1];
                ov.z = o[q * 4 + 2]; ov.w = o[q * 4 + 3];
                if (NTOUT) ntstore4(op + q * 4, ov);
                else *(v4f*)(op + q * 4) = ov;
            }
        }
    }
}

extern "C" void kernel_launch(void* const* d_in, const int* in_sizes, int n_in,
                              void* d_out, int out_size, void* d_ws, size_t ws_size,
                              hipStream_t stream) {
    const float* x     = (const float*)d_in[0];
    const int*   edge  = (const int*)d_in[1];
    const float* W1s   = (const float*)d_in[2];
    const float* W1d   = (const float*)d_in[3];
    const float* att1s = (const float*)d_in[4];
    const float* att1d = (const float*)d_in[5];
    const float* b1    = (const float*)d_in[6];
    const float* W2s   = (const float*)d_in[7];
    const float* W2d   = (const float*)d_in[8];
    const float* att2s = (const float*)d_in[9];
    const float* att2d = (const float*)d_in[10];
    const float* b2    = (const float*)d_in[11];

    const int N = in_sizes[0] / 128;
    const int E = in_sizes[1] / 2;
    const int* srcI = edge;
    const int* dstI = edge + E;

    size_t off = 0;
    auto alloc = [&](size_t bytes) {
        void* p = (char*)d_ws + off;
        off += (bytes + 255) & ~(size_t)255;
        return p;
    };
    int*      offs  = (int*)alloc((size_t)(N + 1) * 4);
    int*      srcs  = (int*)alloc((size_t)E * 4);
    int*      gh    = (int*)alloc(256 * 4);
    int*      bbase = (int*)alloc(257 * 4);
    int*      gcur  = (int*)alloc(256 * 4);
    float*    watt1 = (float*)alloc(128 * 4);
    float*    watt2 = (float*)alloc(128 * 4);
    uint4*    wp1   = (uint4*)alloc(4 * 8 * 64 * 16);        // packed W1s f16
    uint4*    wp2   = (uint4*)alloc(4 * 4 * 64 * 16);        // packed W2s f16
    float*    a_s   = (float*)alloc((size_t)N * 4);
    float*    a_d   = (float*)alloc((size_t)N * 4);
    unsigned* g1h   = (unsigned*)alloc((size_t)N * 128 * 2); // gemm1 out (gather), f16
    unsigned* h1h   = (unsigned*)alloc((size_t)N * 128 * 2); // agg1 out / gemm2 in, f16
    unsigned* g2h   = (unsigned*)alloc((size_t)N * 64 * 2);  // gemm2 out (gather), f16
    u64*      pairs = (u64*)h1h;   // dead until agg1 writes h1h (bsort << agg1)

    hipMemsetAsync(gh, 0, 256 * 4, stream);
    matvec_kernel<<<128, 64, 0, stream>>>(W1d, att1d, watt1, 128);
    matvec_kernel<<<128, 64, 0, stream>>>(W2d, att2d, watt2, 64);
    packw_kernel<128><<<1, 256, 0, stream>>>(W1s, wp1);
    packw_kernel<64><<<1, 256, 0, stream>>>(W2s, wp2);

    const int nbE = (E + 4095) / 4096;
    const int nbuckets = (N + 511) >> 9;
    bhist_kernel<<<nbE, 256, 0, stream>>>(dstI, gh, E);
    bscan_kernel<<<1, 256, 0, stream>>>(gh, bbase, gcur, offs, N, E);
    bscatter_kernel<<<nbE, 256, 0, stream>>>(srcI, dstI, gcur, pairs, E);
    bsort_kernel<<<nbuckets, 512, 0, stream>>>(pairs, bbase, offs, srcs, N);

    int gblk = (N + 63) / 64;
    gemm_att_kernel<128, false><<<gblk, 256, 0, stream>>>(x, wp1, att1s, watt1, g1h, a_s, a_d, N);
    aggregate_kernel<128, true, true, false><<<(N + 3) / 4, 256, 0, stream>>>(
        offs, srcs, g1h, a_s, a_d, b1, h1h, N);
    gemm_att_kernel<64, true><<<gblk, 256, 0, stream>>>(h1h, wp2, att2s, watt2, g2h, a_s, a_d, N);
    aggregate_kernel<64, false, false, true><<<(N + 3) / 4, 256, 0, stream>>>(
        offs, srcs, g2h, a_s, a_d, b2, d_out, N);
}